// Round 5
// baseline (5086.422 us; speedup 1.0000x reference)
//
// tb5 — pure-f32 VALU reference pipeline (bisect anchor, round 5)
#include <hip/hip_runtime.h>
#include <cstdio>

#define DEV __device__ __forceinline__

// ============ f32 LayerNorm, rows of 512 ============
__global__ __launch_bounds__(256) void p5_ln(const float* __restrict__ X,
                                             const float* __restrict__ G,
                                             const float* __restrict__ Bt,
                                             float* __restrict__ O)
{
  const int wid = threadIdx.x >> 6, lane = threadIdx.x & 63;
  const int row = blockIdx.x*4 + wid;
  const float* xr = X + (size_t)row*512 + lane*8;
  float4 v0 = *(const float4*)xr;
  float4 v1 = *(const float4*)(xr+4);
  float xe[8] = {v0.x,v0.y,v0.z,v0.w,v1.x,v1.y,v1.z,v1.w};
  float s = 0.f, sq = 0.f;
#pragma unroll
  for (int j=0;j<8;j++){ s += xe[j]; sq += xe[j]*xe[j]; }
#pragma unroll
  for (int m=1;m<64;m<<=1){ s += __shfl_xor(s,m,64); sq += __shfl_xor(sq,m,64); }
  const float mean = s * (1.f/512.f);
  const float var  = sq * (1.f/512.f) - mean*mean;
  const float rs = rsqrtf(var + 1e-5f);
  float oe[8];
#pragma unroll
  for (int j=0;j<8;j++){
    int c = lane*8 + j;
    oe[j] = (xe[j]-mean)*rs*G[c] + Bt[c];
  }
  float* orow = O + (size_t)row*512 + lane*8;
  *(float4*)orow     = make_float4(oe[0],oe[1],oe[2],oe[3]);
  *(float4*)(orow+4) = make_float4(oe[4],oe[5],oe[6],oe[7]);
}

// ============ f32 GEMM: C[M][N] = A[M][K] @ W[K][N] (+bias)(+res) ============
// W is the ORIGINAL row-major weight — no transpose, no preprocessing.
template<bool BIAS, bool RES>
__global__ __launch_bounds__(256) void p5_mm(const float* __restrict__ A,
                                             const float* __restrict__ W,
                                             const float* __restrict__ bias,
                                             const float* __restrict__ res,
                                             float* __restrict__ C,
                                             int M, int N, int K)
{
  __shared__ float sA[16][65];  // [k][m]
  __shared__ float sB[16][65];  // [k][n]
  const int tid = threadIdx.x;
  const int nbn = N >> 6;
  const int m0 = (blockIdx.x / nbn) << 6;
  const int n0 = (blockIdx.x % nbn) << 6;
  const int tx = tid & 15, ty = tid >> 4;   // tx: n-quad, ty: m-quad
  const int ar = tid >> 2, ac = (tid & 3) << 2;   // A loader: row 0..63, k 0,4,8,12
  const int wr = tid >> 4, wc = (tid & 15) << 2;  // W loader: k 0..15, n 0..60

  float acc[4][4];
#pragma unroll
  for (int i=0;i<4;i++)
#pragma unroll
    for (int j=0;j<4;j++) acc[i][j] = 0.f;

  for (int k0 = 0; k0 < K; k0 += 16) {
    __syncthreads();
    float4 av;
    if (m0 + ar < M) av = *(const float4*)(A + (size_t)(m0+ar)*K + k0 + ac);
    else             av = make_float4(0.f,0.f,0.f,0.f);
    sA[ac+0][ar] = av.x; sA[ac+1][ar] = av.y; sA[ac+2][ar] = av.z; sA[ac+3][ar] = av.w;
    float4 wv = *(const float4*)(W + (size_t)(k0+wr)*N + n0 + wc);
    sB[wr][wc+0] = wv.x; sB[wr][wc+1] = wv.y; sB[wr][wc+2] = wv.z; sB[wr][wc+3] = wv.w;
    __syncthreads();
#pragma unroll
    for (int kk=0; kk<16; ++kk) {
      float a[4], b[4];
#pragma unroll
      for (int i=0;i<4;i++) a[i] = sA[kk][ty*4+i];
#pragma unroll
      for (int j=0;j<4;j++) b[j] = sB[kk][tx*4+j];
#pragma unroll
      for (int i=0;i<4;i++)
#pragma unroll
        for (int j=0;j<4;j++) acc[i][j] += a[i]*b[j];
    }
  }

#pragma unroll
  for (int i=0;i<4;i++) {
    const int m = m0 + ty*4 + i;
    if (m >= M) continue;
#pragma unroll
    for (int j=0;j<4;j++) {
      const int n = n0 + tx*4 + j;
      float v = acc[i][j];
      if (BIAS) v += bias[n];
      if (RES)  v += res[(size_t)m*N + n];
      C[(size_t)m*N + n] = v;
    }
  }
}

// ============ f32 attention, 3-pass, one wave per q-row ============
__global__ __launch_bounds__(256) void p5_attn(
    const float* __restrict__ Q, int ldq,
    const float* __restrict__ Kp, int ldk,
    const float* __restrict__ Vp, int ldv,
    float* __restrict__ O, int ldo,
    int Lq, int Lk, float scale)
{
  __shared__ float sS[4][1024];
  __shared__ float sq[4][64];
  const int tid = threadIdx.x, lane = tid & 63, wid = tid >> 6;
  const int nq = Lq >> 2;
  int bid = blockIdx.x;
  const int qt = bid % nq; bid /= nq;
  const int hh = bid & 7; const int bb = bid >> 3;
  const int qrow = qt*4 + wid;

  const float* Qr = Q + ((size_t)bb*Lq + qrow)*ldq + hh*64;
  sq[wid][lane] = Qr[lane];
  __syncthreads();

  // pass 1: scores
  float mpart = -1e30f;
  for (int j = lane; j < Lk; j += 64) {
    const float* Kr = Kp + ((size_t)bb*Lk + j)*ldk + hh*64;
    float s = 0.f;
#pragma unroll
    for (int d=0; d<64; ++d) s += sq[wid][d]*Kr[d];
    s *= scale;
    sS[wid][j] = s;
    mpart = fmaxf(mpart, s);
  }
#pragma unroll
  for (int m=1;m<64;m<<=1) mpart = fmaxf(mpart, __shfl_xor(mpart,m,64));

  // pass 2: exp + sum
  float lpart = 0.f;
  for (int j = lane; j < Lk; j += 64) {
    float e = expf(sS[wid][j] - mpart);
    sS[wid][j] = e;
    lpart += e;
  }
#pragma unroll
  for (int m=1;m<64;m<<=1) lpart += __shfl_xor(lpart,m,64);
  __syncthreads();

  // pass 3: o[d], d = lane
  float o = 0.f;
  for (int j = 0; j < Lk; ++j)
    o += sS[wid][j] * Vp[((size_t)bb*Lk + j)*ldv + hh*64 + lane];
  O[((size_t)bb*Lq + qrow)*ldo + hh*64 + lane] = o / lpart;
}

// ============ f32 GEGLU: G[m][0..2047] = P[m][n]*gelu(P[m][2048+n]) ============
__global__ __launch_bounds__(256) void p5_gg(const float* __restrict__ P,
                                             float* __restrict__ Gt)
{
  size_t idx = (size_t)blockIdx.x*256 + threadIdx.x;
  size_t m = idx / 512;
  size_t n = (idx % 512) * 4;
  float4 v = *(const float4*)(P + m*4096 + n);
  float4 g = *(const float4*)(P + m*4096 + 2048 + n);
  float ve[4] = {v.x,v.y,v.z,v.w};
  float ge[4] = {g.x,g.y,g.z,g.w};
  float re[4];
#pragma unroll
  for (int j=0;j<4;j++){
    float gel = 0.5f*ge[j]*(1.f + erff(ge[j]*0.70710678118f));
    re[j] = ve[j]*gel;
  }
  *(float4*)(Gt + m*2048 + n) = make_float4(re[0],re[1],re[2],re[3]);
}

// ============ host ============
extern "C" void kernel_launch(void* const* d_in, const int* in_sizes, int n_in,
                              void* d_out, int out_size, void* d_ws, size_t ws_size,
                              hipStream_t stream)
{
  (void)in_sizes; (void)n_in; (void)out_size;
  printf("[tb5] kernel_launch build=r5-f32probe ws=%zu\n", ws_size);
  fprintf(stderr, "[tb5] kernel_launch build=r5-f32probe ws=%zu\n", ws_size);

  const float* x    = (const float*)d_in[0];
  const float* ctx  = (const float*)d_in[1];
  const float* ln1g = (const float*)d_in[2];
  const float* ln1b = (const float*)d_in[3];
  const float* ln2g = (const float*)d_in[4];
  const float* ln2b = (const float*)d_in[5];
  const float* ln3g = (const float*)d_in[6];
  const float* ln3b = (const float*)d_in[7];
  const float* wq1  = (const float*)d_in[8];
  const float* wk1  = (const float*)d_in[9];
  const float* wv1  = (const float*)d_in[10];
  const float* wo1  = (const float*)d_in[11];
  const float* bo1  = (const float*)d_in[12];
  const float* wq2  = (const float*)d_in[13];
  const float* wk2  = (const float*)d_in[14];
  const float* wv2  = (const float*)d_in[15];
  const float* wo2  = (const float*)d_in[16];
  const float* bo2  = (const float*)d_in[17];
  const float* w1   = (const float*)d_in[18];
  const float* b1   = (const float*)d_in[19];
  const float* w2   = (const float*)d_in[20];
  const float* b2   = (const float*)d_in[21];
  float* out = (float*)d_out;

  char* ws = (char*)d_ws;
  size_t off = 0;
  auto alloc = [&](size_t bytes)->void* {
    void* p = ws + off; off += (bytes + 255) & ~(size_t)255; return p;
  };
  float* h   = (float*)alloc((size_t)8192*512*4);   // 16 MB
  float* q1  = (float*)alloc((size_t)8192*512*4);
  float* k1  = (float*)alloc((size_t)8192*512*4);
  float* v1  = (float*)alloc((size_t)8192*512*4);
  float* ob  = (float*)alloc((size_t)8192*512*4);   // attn out (reused)
  float* x1  = (float*)alloc((size_t)8192*512*4);
  float* q2  = (float*)alloc((size_t)8192*512*4);
  float* k2  = (float*)alloc((size_t)616*512*4);
  float* v2  = (float*)alloc((size_t)616*512*4);
  float* pch = (float*)alloc((size_t)2048*4096*4);  // FF chunk p (33.5 MB)
  float* gch = (float*)alloc((size_t)2048*2048*4);  // FF chunk geglu (16.8 MB)

  dim3 blk(256);

  // ---- self attention ----
  p5_ln<<<dim3(2048), blk, 0, stream>>>(x, ln1g, ln1b, h);
  p5_mm<false,false><<<dim3(128*8), blk, 0, stream>>>(h, wq1, nullptr, nullptr, q1, 8192, 512, 512);
  p5_mm<false,false><<<dim3(128*8), blk, 0, stream>>>(h, wk1, nullptr, nullptr, k1, 8192, 512, 512);
  p5_mm<false,false><<<dim3(128*8), blk, 0, stream>>>(h, wv1, nullptr, nullptr, v1, 8192, 512, 512);
  p5_attn<<<dim3(16384), blk, 0, stream>>>(q1, 512, k1, 512, v1, 512, ob, 512, 1024, 1024, 0.125f);
  p5_mm<true,true><<<dim3(128*8), blk, 0, stream>>>(ob, wo1, bo1, x, x1, 8192, 512, 512);

  // ---- cross attention ----
  p5_ln<<<dim3(2048), blk, 0, stream>>>(x1, ln2g, ln2b, h);
  p5_mm<false,false><<<dim3(128*8), blk, 0, stream>>>(h, wq2, nullptr, nullptr, q2, 8192, 512, 512);
  p5_mm<false,false><<<dim3(10*8), blk, 0, stream>>>(ctx, wk2, nullptr, nullptr, k2, 616, 512, 768);
  p5_mm<false,false><<<dim3(10*8), blk, 0, stream>>>(ctx, wv2, nullptr, nullptr, v2, 616, 512, 768);
  p5_attn<<<dim3(16384), blk, 0, stream>>>(q2, 512, k2, 512, v2, 512, ob, 512, 1024, 77, 0.125f);
  p5_mm<true,true><<<dim3(128*8), blk, 0, stream>>>(ob, wo2, bo2, x1, out, 8192, 512, 512);

  // ---- feed-forward (GEGLU), 4 chunks of 2048 rows ----
  p5_ln<<<dim3(2048), blk, 0, stream>>>(out, ln3g, ln3b, h);
  for (int c = 0; c < 4; ++c) {
    const size_t r0 = (size_t)c*2048;
    p5_mm<true,false><<<dim3(32*64), blk, 0, stream>>>(h + r0*512, w1, b1, nullptr, pch, 2048, 4096, 512);
    p5_gg<<<dim3(4096), blk, 0, stream>>>(pch, gch);
    p5_mm<true,true><<<dim3(32*8), blk, 0, stream>>>(gch, w2, b2, out + r0*512, out + r0*512, 2048, 512, 2048);
  }
}

// Round 6
// 2398.312 us; speedup vs baseline: 2.1208x; 2.1208x over previous
//
// tb6 — f32 anchor + MFMA flash attention only (bisect round 6)
#include <hip/hip_runtime.h>
#include <hip/hip_bf16.h>
#include <cstdio>

using bf16 = __hip_bfloat16;
typedef __attribute__((ext_vector_type(8))) short short8;
typedef __attribute__((ext_vector_type(4))) short short4v;
typedef __attribute__((ext_vector_type(4))) float f32x4;

#define DEV __device__ __forceinline__

DEV short f2b(float x){ __hip_bfloat16 h = __float2bfloat16(x); return __builtin_bit_cast(short, h); }
DEV float b2f(short s){ __hip_bfloat16 h = __builtin_bit_cast(__hip_bfloat16, s); return __bfloat162float(h); }

// ============ f32 LayerNorm, rows of 512 ============
__global__ __launch_bounds__(256) void p5_ln(const float* __restrict__ X,
                                             const float* __restrict__ G,
                                             const float* __restrict__ Bt,
                                             float* __restrict__ O)
{
  const int wid = threadIdx.x >> 6, lane = threadIdx.x & 63;
  const int row = blockIdx.x*4 + wid;
  const float* xr = X + (size_t)row*512 + lane*8;
  float4 v0 = *(const float4*)xr;
  float4 v1 = *(const float4*)(xr+4);
  float xe[8] = {v0.x,v0.y,v0.z,v0.w,v1.x,v1.y,v1.z,v1.w};
  float s = 0.f, sq = 0.f;
#pragma unroll
  for (int j=0;j<8;j++){ s += xe[j]; sq += xe[j]*xe[j]; }
#pragma unroll
  for (int m=1;m<64;m<<=1){ s += __shfl_xor(s,m,64); sq += __shfl_xor(sq,m,64); }
  const float mean = s * (1.f/512.f);
  const float var  = sq * (1.f/512.f) - mean*mean;
  const float rs = rsqrtf(var + 1e-5f);
  float oe[8];
#pragma unroll
  for (int j=0;j<8;j++){
    int c = lane*8 + j;
    oe[j] = (xe[j]-mean)*rs*G[c] + Bt[c];
  }
  float* orow = O + (size_t)row*512 + lane*8;
  *(float4*)orow     = make_float4(oe[0],oe[1],oe[2],oe[3]);
  *(float4*)(orow+4) = make_float4(oe[4],oe[5],oe[6],oe[7]);
}

// ============ f32 GEMM: C[M][N] = A[M][K] @ W[K][N] (+bias)(+res) ============
template<bool BIAS, bool RES>
__global__ __launch_bounds__(256) void p5_mm(const float* __restrict__ A,
                                             const float* __restrict__ W,
                                             const float* __restrict__ bias,
                                             const float* __restrict__ res,
                                             float* __restrict__ C,
                                             int M, int N, int K)
{
  __shared__ float sA[16][65];
  __shared__ float sB[16][65];
  const int tid = threadIdx.x;
  const int nbn = N >> 6;
  const int m0 = (blockIdx.x / nbn) << 6;
  const int n0 = (blockIdx.x % nbn) << 6;
  const int tx = tid & 15, ty = tid >> 4;
  const int ar = tid >> 2, ac = (tid & 3) << 2;
  const int wr = tid >> 4, wc = (tid & 15) << 2;

  float acc[4][4];
#pragma unroll
  for (int i=0;i<4;i++)
#pragma unroll
    for (int j=0;j<4;j++) acc[i][j] = 0.f;

  for (int k0 = 0; k0 < K; k0 += 16) {
    __syncthreads();
    float4 av;
    if (m0 + ar < M) av = *(const float4*)(A + (size_t)(m0+ar)*K + k0 + ac);
    else             av = make_float4(0.f,0.f,0.f,0.f);
    sA[ac+0][ar] = av.x; sA[ac+1][ar] = av.y; sA[ac+2][ar] = av.z; sA[ac+3][ar] = av.w;
    float4 wv = *(const float4*)(W + (size_t)(k0+wr)*N + n0 + wc);
    sB[wr][wc+0] = wv.x; sB[wr][wc+1] = wv.y; sB[wr][wc+2] = wv.z; sB[wr][wc+3] = wv.w;
    __syncthreads();
#pragma unroll
    for (int kk=0; kk<16; ++kk) {
      float a[4], b[4];
#pragma unroll
      for (int i=0;i<4;i++) a[i] = sA[kk][ty*4+i];
#pragma unroll
      for (int j=0;j<4;j++) b[j] = sB[kk][tx*4+j];
#pragma unroll
      for (int i=0;i<4;i++)
#pragma unroll
        for (int j=0;j<4;j++) acc[i][j] += a[i]*b[j];
    }
  }

#pragma unroll
  for (int i=0;i<4;i++) {
    const int m = m0 + ty*4 + i;
    if (m >= M) continue;
#pragma unroll
    for (int j=0;j<4;j++) {
      const int n = n0 + tx*4 + j;
      float v = acc[i][j];
      if (BIAS) v += bias[n];
      if (RES)  v += res[(size_t)m*N + n];
      C[(size_t)m*N + n] = v;
    }
  }
}

// ============ f32 -> bf16 hi/lo, flat ============
__global__ __launch_bounds__(256) void tb_split(const float* __restrict__ in,
                                                bf16* __restrict__ oh,
                                                bf16* __restrict__ ol, int n4)
{
  int i = blockIdx.x*256 + threadIdx.x;
  if (i >= n4) return;
  float4 v = ((const float4*)in)[i];
  float e[4] = {v.x, v.y, v.z, v.w};
  short4v sh, sl;
#pragma unroll
  for (int j=0;j<4;j++){
    short h = f2b(e[j]);
    sh[j] = h;
    sl[j] = f2b(e[j] - b2f(h));
  }
  ((short4v*)oh)[i] = sh;
  ((short4v*)ol)[i] = sl;
}

// ============ MFMA flash attention, hi/lo operands, f32 output ============
template<bool MASK>
__global__ __launch_bounds__(256) void tb_fa(
    const bf16* __restrict__ Qh, const bf16* __restrict__ Ql, int ldq,
    const bf16* __restrict__ Kh, const bf16* __restrict__ Kl, int ldk,
    const bf16* __restrict__ Vh, const bf16* __restrict__ Vl, int ldv,
    float* __restrict__ O, int ldo,
    int Lq, int Lk, float scale)
{
  __shared__ bf16 sKh[32][72];
  __shared__ bf16 sKl[32][72];
  __shared__ bf16 sVTh[64][40];
  __shared__ bf16 sVTl[64][40];
  __shared__ bf16 sPh[4][16][48];
  __shared__ bf16 sPl[4][16][48];
  const int tid = threadIdx.x, lane = tid & 63, wid = tid >> 6;
  const int nq = Lq >> 6;
  int bid = blockIdx.x;
  const int qt = bid % nq; bid /= nq;
  const int hh = bid & 7; const int bb = bid >> 3;

  const bf16* Qbh = Qh + (size_t)bb*Lq*ldq + hh*64;
  const bf16* Qbl = Ql + (size_t)bb*Lq*ldq + hh*64;
  const bf16* Kbh = Kh + (size_t)bb*Lk*ldk + hh*64;
  const bf16* Kbl = Kl + (size_t)bb*Lk*ldk + hh*64;
  const bf16* Vbh = Vh + (size_t)bb*Lk*ldv + hh*64;
  const bf16* Vbl = Vl + (size_t)bb*Lk*ldv + hh*64;

  const int qrow = qt*64 + wid*16;
  const int fr = lane & 15, fg = lane >> 4;

  short8 aqh[2], aql[2];
#pragma unroll
  for (int c=0;c<2;c++){
    aqh[c] = *(const short8*)(Qbh + (size_t)(qrow + fr)*ldq + c*32 + fg*8);
    aql[c] = *(const short8*)(Qbl + (size_t)(qrow + fr)*ldq + c*32 + fg*8);
  }

  f32x4 oacc[4];
#pragma unroll
  for (int j=0;j<4;j++) oacc[j] = (f32x4)0.f;
  float mrun[4] = {-1e30f,-1e30f,-1e30f,-1e30f};
  float lrun[4] = {0.f,0.f,0.f,0.f};
  const float LOG2E = 1.44269504089f;

  const int nkc = (Lk + 31) >> 5;
  for (int kc = 0; kc < nkc; ++kc) {
    const int k0 = kc << 5;
    __syncthreads();
    {
      const int krow = tid >> 3;
      const int dh0  = (tid & 7) << 3;
      int gk = k0 + krow; if (gk > Lk-1) gk = Lk-1;
      short8 kh = *(const short8*)(Kbh + (size_t)gk*ldk + dh0);
      short8 kl = *(const short8*)(Kbl + (size_t)gk*ldk + dh0);
      short8 vh = *(const short8*)(Vbh + (size_t)gk*ldv + dh0);
      short8 vl = *(const short8*)(Vbl + (size_t)gk*ldv + dh0);
      *(short8*)(&sKh[krow][dh0]) = kh;
      *(short8*)(&sKl[krow][dh0]) = kl;
#pragma unroll
      for (int j=0;j<8;j++){
        sVTh[dh0+j][krow] = __builtin_bit_cast(bf16, (short)vh[j]);
        sVTl[dh0+j][krow] = __builtin_bit_cast(bf16, (short)vl[j]);
      }
    }
    __syncthreads();

    f32x4 sfr[2];
#pragma unroll
    for (int nt=0; nt<2; ++nt) {
      f32x4 sacc = (f32x4)0.f;
#pragma unroll
      for (int c=0;c<2;c++) {
        short8 bkh = *(const short8*)(&sKh[nt*16 + fr][c*32 + fg*8]);
        short8 bkl = *(const short8*)(&sKl[nt*16 + fr][c*32 + fg*8]);
        sacc = __builtin_amdgcn_mfma_f32_16x16x32_bf16(aqh[c], bkh, sacc, 0,0,0);
        sacc = __builtin_amdgcn_mfma_f32_16x16x32_bf16(aql[c], bkh, sacc, 0,0,0);
        sacc = __builtin_amdgcn_mfma_f32_16x16x32_bf16(aqh[c], bkl, sacc, 0,0,0);
      }
      sfr[nt] = sacc;
    }

    float pv0[4], pv1[4], mnew[4];
#pragma unroll
    for (int r=0;r<4;r++){
      float s0 = sfr[0][r]*scale, s1 = sfr[1][r]*scale;
      if (MASK) {
        if (k0 + fr      >= Lk) s0 = -1e30f;
        if (k0 + 16 + fr >= Lk) s1 = -1e30f;
      }
      pv0[r] = s0; pv1[r] = s1;
      float mx = fmaxf(s0, s1);
#pragma unroll
      for (int m=1;m<16;m<<=1) mx = fmaxf(mx, __shfl_xor(mx,m,64));
      mnew[r] = fmaxf(mrun[r], mx);
    }
#pragma unroll
    for (int r=0;r<4;r++){
      float sc = exp2f((mrun[r]-mnew[r])*LOG2E);
      mrun[r] = mnew[r];
      float p0 = exp2f((pv0[r]-mnew[r])*LOG2E);
      float p1 = exp2f((pv1[r]-mnew[r])*LOG2E);
      float ladd = p0 + p1;
#pragma unroll
      for (int m=1;m<16;m<<=1) ladd += __shfl_xor(ladd,m,64);
      lrun[r] = lrun[r]*sc + ladd;
#pragma unroll
      for (int j=0;j<4;j++) oacc[j][r] *= sc;
      short h0 = f2b(p0), h1 = f2b(p1);
      sPh[wid][fg*4+r][fr]       = __builtin_bit_cast(bf16, h0);
      sPh[wid][fg*4+r][16 + fr]  = __builtin_bit_cast(bf16, h1);
      sPl[wid][fg*4+r][fr]       = __float2bfloat16(p0 - b2f(h0));
      sPl[wid][fg*4+r][16 + fr]  = __float2bfloat16(p1 - b2f(h1));
    }

    asm volatile("s_waitcnt lgkmcnt(0)" ::: "memory");
    short8 pah = *(const short8*)(&sPh[wid][fr][fg*8]);
    short8 pal = *(const short8*)(&sPl[wid][fr][fg*8]);
#pragma unroll
    for (int ni=0; ni<4; ++ni) {
      short8 bvh = *(const short8*)(&sVTh[ni*16 + fr][fg*8]);
      short8 bvl = *(const short8*)(&sVTl[ni*16 + fr][fg*8]);
      oacc[ni] = __builtin_amdgcn_mfma_f32_16x16x32_bf16(pah, bvh, oacc[ni], 0,0,0);
      oacc[ni] = __builtin_amdgcn_mfma_f32_16x16x32_bf16(pal, bvh, oacc[ni], 0,0,0);
      oacc[ni] = __builtin_amdgcn_mfma_f32_16x16x32_bf16(pah, bvl, oacc[ni], 0,0,0);
    }
  }

  float inv[4];
#pragma unroll
  for (int r=0;r<4;r++) inv[r] = 1.f / lrun[r];
  const size_t orow0 = (size_t)bb*Lq + qt*64 + wid*16;
#pragma unroll
  for (int ni=0; ni<4; ++ni)
#pragma unroll
    for (int r=0;r<4;r++)
      O[(orow0 + fg*4 + r)*ldo + hh*64 + ni*16 + fr] = oacc[ni][r]*inv[r];
}

// ============ f32 GEGLU ============
__global__ __launch_bounds__(256) void p5_gg(const float* __restrict__ P,
                                             float* __restrict__ Gt)
{
  size_t idx = (size_t)blockIdx.x*256 + threadIdx.x;
  size_t m = idx / 512;
  size_t n = (idx % 512) * 4;
  float4 v = *(const float4*)(P + m*4096 + n);
  float4 g = *(const float4*)(P + m*4096 + 2048 + n);
  float ve[4] = {v.x,v.y,v.z,v.w};
  float ge[4] = {g.x,g.y,g.z,g.w};
  float re[4];
#pragma unroll
  for (int j=0;j<4;j++){
    float gel = 0.5f*ge[j]*(1.f + erff(ge[j]*0.70710678118f));
    re[j] = ve[j]*gel;
  }
  *(float4*)(Gt + m*2048 + n) = make_float4(re[0],re[1],re[2],re[3]);
}

// ============ host ============
extern "C" void kernel_launch(void* const* d_in, const int* in_sizes, int n_in,
                              void* d_out, int out_size, void* d_ws, size_t ws_size,
                              hipStream_t stream)
{
  (void)in_sizes; (void)n_in; (void)out_size;
  printf("[tb6] kernel_launch build=r6-mfma-attn ws=%zu\n", ws_size);

  const float* x    = (const float*)d_in[0];
  const float* ctx  = (const float*)d_in[1];
  const float* ln1g = (const float*)d_in[2];
  const float* ln1b = (const float*)d_in[3];
  const float* ln2g = (const float*)d_in[4];
  const float* ln2b = (const float*)d_in[5];
  const float* ln3g = (const float*)d_in[6];
  const float* ln3b = (const float*)d_in[7];
  const float* wq1  = (const float*)d_in[8];
  const float* wk1  = (const float*)d_in[9];
  const float* wv1  = (const float*)d_in[10];
  const float* wo1  = (const float*)d_in[11];
  const float* bo1  = (const float*)d_in[12];
  const float* wq2  = (const float*)d_in[13];
  const float* wk2  = (const float*)d_in[14];
  const float* wv2  = (const float*)d_in[15];
  const float* wo2  = (const float*)d_in[16];
  const float* bo2  = (const float*)d_in[17];
  const float* w1   = (const float*)d_in[18];
  const float* b1   = (const float*)d_in[19];
  const float* w2   = (const float*)d_in[20];
  const float* b2   = (const float*)d_in[21];
  float* out = (float*)d_out;

  char* ws = (char*)d_ws;
  size_t off = 0;
  auto alloc = [&](size_t bytes)->void* {
    void* p = ws + off; off += (bytes + 255) & ~(size_t)255; return p;
  };
  float* h   = (float*)alloc((size_t)8192*512*4);
  float* q1  = (float*)alloc((size_t)8192*512*4);
  float* k1  = (float*)alloc((size_t)8192*512*4);
  float* v1  = (float*)alloc((size_t)8192*512*4);
  float* ob  = (float*)alloc((size_t)8192*512*4);
  float* x1  = (float*)alloc((size_t)8192*512*4);
  float* pch = (float*)alloc((size_t)2048*4096*4);
  float* gch = (float*)alloc((size_t)2048*2048*4);
  bf16 *qh = (bf16*)alloc((size_t)8192*512*2), *ql = (bf16*)alloc((size_t)8192*512*2);
  bf16 *kh = (bf16*)alloc((size_t)8192*512*2), *kl = (bf16*)alloc((size_t)8192*512*2);
  bf16 *vh = (bf16*)alloc((size_t)8192*512*2), *vl = (bf16*)alloc((size_t)8192*512*2);
  // cross-attn K/V (616 rows) reuse k1/v1 f32 slots' tails? keep separate:
  float* k2  = (float*)alloc((size_t)616*512*4);
  float* v2  = (float*)alloc((size_t)616*512*4);
  bf16 *k2h = (bf16*)alloc((size_t)616*512*2), *k2l = (bf16*)alloc((size_t)616*512*2);
  bf16 *v2h = (bf16*)alloc((size_t)616*512*2), *v2l = (bf16*)alloc((size_t)616*512*2);

  dim3 blk(256);

  // ---- self attention ----
  p5_ln<<<dim3(2048), blk, 0, stream>>>(x, ln1g, ln1b, h);
  p5_mm<false,false><<<dim3(128*8), blk, 0, stream>>>(h, wq1, nullptr, nullptr, q1, 8192, 512, 512);
  p5_mm<false,false><<<dim3(128*8), blk, 0, stream>>>(h, wk1, nullptr, nullptr, k1, 8192, 512, 512);
  p5_mm<false,false><<<dim3(128*8), blk, 0, stream>>>(h, wv1, nullptr, nullptr, v1, 8192, 512, 512);
  tb_split<<<dim3(4096), blk, 0, stream>>>(q1, qh, ql, 8192*512/4);
  tb_split<<<dim3(4096), blk, 0, stream>>>(k1, kh, kl, 8192*512/4);
  tb_split<<<dim3(4096), blk, 0, stream>>>(v1, vh, vl, 8192*512/4);
  tb_fa<false><<<dim3(1024), blk, 0, stream>>>(qh, ql, 512, kh, kl, 512, vh, vl, 512,
                                               ob, 512, 1024, 1024, 0.125f);
  p5_mm<true,true><<<dim3(128*8), blk, 0, stream>>>(ob, wo1, bo1, x, x1, 8192, 512, 512);

  // ---- cross attention ----
  p5_ln<<<dim3(2048), blk, 0, stream>>>(x1, ln2g, ln2b, h);
  p5_mm<false,false><<<dim3(128*8), blk, 0, stream>>>(h, wq2, nullptr, nullptr, q1, 8192, 512, 512);
  p5_mm<false,false><<<dim3(10*8), blk, 0, stream>>>(ctx, wk2, nullptr, nullptr, k2, 616, 512, 768);
  p5_mm<false,false><<<dim3(10*8), blk, 0, stream>>>(ctx, wv2, nullptr, nullptr, v2, 616, 512, 768);
  tb_split<<<dim3(4096), blk, 0, stream>>>(q1, qh, ql, 8192*512/4);
  tb_split<<<dim3(308), blk, 0, stream>>>(k2, k2h, k2l, 616*512/4);
  tb_split<<<dim3(308), blk, 0, stream>>>(v2, v2h, v2l, 616*512/4);
  tb_fa<true><<<dim3(1024), blk, 0, stream>>>(qh, ql, 512, k2h, k2l, 512, v2h, v2l, 512,
                                              ob, 512, 1024, 77, 0.125f);
  p5_mm<true,true><<<dim3(128*8), blk, 0, stream>>>(ob, wo2, bo2, x1, out, 8192, 512, 512);

  // ---- feed-forward (GEGLU), 4 chunks of 2048 rows ----
  p5_ln<<<dim3(2048), blk, 0, stream>>>(out, ln3g, ln3b, h);
  for (int c = 0; c < 4; ++c) {
    const size_t r0 = (size_t)c*2048;
    p5_mm<true,false><<<dim3(32*64), blk, 0, stream>>>(h + r0*512, w1, b1, nullptr, pch, 2048, 4096, 512);
    p5_gg<<<dim3(4096), blk, 0, stream>>>(pch, gch);
    p5_mm<true,true><<<dim3(32*8), blk, 0, stream>>>(gch, w2, b2, out + r0*512, out + r0*512, 2048, 512, 2048);
  }
}

// Round 7
// 1954.177 us; speedup vs baseline: 2.6028x; 1.2273x over previous
//
// tb7 — MFMA hi/lo GEMMs from exonerated building blocks (round 7)
#include <hip/hip_runtime.h>
#include <hip/hip_bf16.h>
#include <cstdio>

using bf16 = __hip_bfloat16;
typedef __attribute__((ext_vector_type(8))) short short8;
typedef __attribute__((ext_vector_type(4))) short short4v;
typedef __attribute__((ext_vector_type(4))) float f32x4;

#define DEV __device__ __forceinline__

DEV short f2b(float x){ __hip_bfloat16 h = __float2bfloat16(x); return __builtin_bit_cast(short, h); }
DEV float b2f(short s){ __hip_bfloat16 h = __builtin_bit_cast(__hip_bfloat16, s); return __bfloat162float(h); }

// ============ f32 LayerNorm, rows of 512 ============
__global__ __launch_bounds__(256) void p5_ln(const float* __restrict__ X,
                                             const float* __restrict__ G,
                                             const float* __restrict__ Bt,
                                             float* __restrict__ O)
{
  const int wid = threadIdx.x >> 6, lane = threadIdx.x & 63;
  const int row = blockIdx.x*4 + wid;
  const float* xr = X + (size_t)row*512 + lane*8;
  float4 v0 = *(const float4*)xr;
  float4 v1 = *(const float4*)(xr+4);
  float xe[8] = {v0.x,v0.y,v0.z,v0.w,v1.x,v1.y,v1.z,v1.w};
  float s = 0.f, sq = 0.f;
#pragma unroll
  for (int j=0;j<8;j++){ s += xe[j]; sq += xe[j]*xe[j]; }
#pragma unroll
  for (int m=1;m<64;m<<=1){ s += __shfl_xor(s,m,64); sq += __shfl_xor(sq,m,64); }
  const float mean = s * (1.f/512.f);
  const float var  = sq * (1.f/512.f) - mean*mean;
  const float rs = rsqrtf(var + 1e-5f);
  float oe[8];
#pragma unroll
  for (int j=0;j<8;j++){
    int c = lane*8 + j;
    oe[j] = (xe[j]-mean)*rs*G[c] + Bt[c];
  }
  float* orow = O + (size_t)row*512 + lane*8;
  *(float4*)orow     = make_float4(oe[0],oe[1],oe[2],oe[3]);
  *(float4*)(orow+4) = make_float4(oe[4],oe[5],oe[6],oe[7]);
}

// ============ f32 -> bf16 hi/lo, flat ============
__global__ __launch_bounds__(256) void tb_split(const float* __restrict__ in,
                                                bf16* __restrict__ oh,
                                                bf16* __restrict__ ol, int n4)
{
  int i = blockIdx.x*256 + threadIdx.x;
  if (i >= n4) return;
  float4 v = ((const float4*)in)[i];
  float e[4] = {v.x, v.y, v.z, v.w};
  short4v sh, sl;
#pragma unroll
  for (int j=0;j<4;j++){
    short h = f2b(e[j]);
    sh[j] = h;
    sl[j] = f2b(e[j] - b2f(h));
  }
  ((short4v*)oh)[i] = sh;
  ((short4v*)ol)[i] = sl;
}

// ============ MFMA hi/lo GEMM: C[M][N] = A[M][K](f32) @ (Wh+Wl)[K][N] ============
// A split to hi/lo in-kernel; B staged [n][k] via transposing ds_writes.
template<bool BIAS, bool RES>
__global__ __launch_bounds__(256) void mm7(
    const float* __restrict__ A,
    const bf16* __restrict__ Wh, const bf16* __restrict__ Wl,
    const float* __restrict__ bias,
    const float* __restrict__ res,
    float* __restrict__ C,
    int M, int N, int K)
{
  __shared__ bf16 sAh[128][40];
  __shared__ bf16 sAl[128][40];
  __shared__ bf16 sBh[128][40];   // [n][k]
  __shared__ bf16 sBl[128][40];
  const int tid = threadIdx.x, lane = tid & 63;
  const int nbn = N >> 7;
  const int m0 = (blockIdx.x / nbn) << 7;
  const int n0 = (blockIdx.x % nbn) << 7;
  const int wid = tid >> 6;
  const int wr = (wid >> 1) << 6, wc = (wid & 1) << 6;
  const int fr = lane & 15, fgk = (lane >> 4) << 3;

  f32x4 acc[4][4];
#pragma unroll
  for (int i=0;i<4;i++)
#pragma unroll
    for (int j=0;j<4;j++) acc[i][j] = (f32x4)0.f;

  for (int k0 = 0; k0 < K; k0 += 32) {
    __syncthreads();
    // ---- stage A: 128 rows x 32 k, f32 -> bf16 hi/lo ----
#pragma unroll
    for (int i = 0; i < 4; ++i) {
      const int li = i*256 + tid;           // float4 index
      const int row = li >> 3;              // 8 float4 per row of 32
      const int kc  = (li & 7) << 2;        // k offset 0,4,..,28
      int ga = m0 + row; if (ga >= M) ga = M - 1;
      float4 av = *(const float4*)(A + (size_t)ga*K + k0 + kc);
      float e[4] = {av.x, av.y, av.z, av.w};
      short4v sh, sl;
#pragma unroll
      for (int j=0;j<4;j++){
        short h = f2b(e[j]);
        sh[j] = h;
        sl[j] = f2b(e[j] - b2f(h));
      }
      *(short4v*)(&sAh[row][kc]) = sh;
      *(short4v*)(&sAl[row][kc]) = sl;
    }
    // ---- stage B: 32 k-rows x 128 n, bf16 pair, transpose to [n][k] ----
#pragma unroll
    for (int i = 0; i < 2; ++i) {
      const int li = i*256 + tid;           // short8 index
      const int kr = li >> 4;               // 16 short8 per k-row of 128
      const int nc = (li & 15) << 3;        // n offset 0..120
      const size_t goff = (size_t)(k0 + kr)*N + n0 + nc;
      short8 bh = *(const short8*)(Wh + goff);
      short8 bl = *(const short8*)(Wl + goff);
#pragma unroll
      for (int j=0;j<8;j++){
        sBh[nc+j][kr] = __builtin_bit_cast(bf16, (short)bh[j]);
        sBl[nc+j][kr] = __builtin_bit_cast(bf16, (short)bl[j]);
      }
    }
    __syncthreads();

    short8 avh[4], avl[4], bvh[4], bvl[4];
#pragma unroll
    for (int i=0;i<4;i++) {
      avh[i] = *(const short8*)(&sAh[wr + i*16 + fr][fgk]);
      avl[i] = *(const short8*)(&sAl[wr + i*16 + fr][fgk]);
    }
#pragma unroll
    for (int j=0;j<4;j++) {
      bvh[j] = *(const short8*)(&sBh[wc + j*16 + fr][fgk]);
      bvl[j] = *(const short8*)(&sBl[wc + j*16 + fr][fgk]);
    }
#pragma unroll
    for (int i=0;i<4;i++)
#pragma unroll
      for (int j=0;j<4;j++) {
        acc[i][j] = __builtin_amdgcn_mfma_f32_16x16x32_bf16(avh[i], bvh[j], acc[i][j], 0,0,0);
        acc[i][j] = __builtin_amdgcn_mfma_f32_16x16x32_bf16(avl[i], bvh[j], acc[i][j], 0,0,0);
        acc[i][j] = __builtin_amdgcn_mfma_f32_16x16x32_bf16(avh[i], bvl[j], acc[i][j], 0,0,0);
      }
  }

  const int cr0 = (lane >> 4) << 2, cc = lane & 15;
#pragma unroll
  for (int i=0;i<4;i++) {
#pragma unroll
    for (int r=0;r<4;r++) {
      const int grow = m0 + wr + i*16 + cr0 + r;
      if (grow >= M) continue;
#pragma unroll
      for (int j=0;j<4;j++) {
        const int gcol = n0 + wc + j*16 + cc;
        float v = acc[i][j][r];
        if (BIAS) v += bias[gcol];
        if (RES)  v += res[(size_t)grow*N + gcol];
        C[(size_t)grow*N + gcol] = v;
      }
    }
  }
}

// ============ MFMA flash attention, hi/lo operands, f32 output ============
template<bool MASK>
__global__ __launch_bounds__(256) void tb_fa(
    const bf16* __restrict__ Qh, const bf16* __restrict__ Ql, int ldq,
    const bf16* __restrict__ Kh, const bf16* __restrict__ Kl, int ldk,
    const bf16* __restrict__ Vh, const bf16* __restrict__ Vl, int ldv,
    float* __restrict__ O, int ldo,
    int Lq, int Lk, float scale)
{
  __shared__ bf16 sKh[32][72];
  __shared__ bf16 sKl[32][72];
  __shared__ bf16 sVTh[64][40];
  __shared__ bf16 sVTl[64][40];
  __shared__ bf16 sPh[4][16][48];
  __shared__ bf16 sPl[4][16][48];
  const int tid = threadIdx.x, lane = tid & 63, wid = tid >> 6;
  const int nq = Lq >> 6;
  int bid = blockIdx.x;
  const int qt = bid % nq; bid /= nq;
  const int hh = bid & 7; const int bb = bid >> 3;

  const bf16* Qbh = Qh + (size_t)bb*Lq*ldq + hh*64;
  const bf16* Qbl = Ql + (size_t)bb*Lq*ldq + hh*64;
  const bf16* Kbh = Kh + (size_t)bb*Lk*ldk + hh*64;
  const bf16* Kbl = Kl + (size_t)bb*Lk*ldk + hh*64;
  const bf16* Vbh = Vh + (size_t)bb*Lk*ldv + hh*64;
  const bf16* Vbl = Vl + (size_t)bb*Lk*ldv + hh*64;

  const int qrow = qt*64 + wid*16;
  const int fr = lane & 15, fg = lane >> 4;

  short8 aqh[2], aql[2];
#pragma unroll
  for (int c=0;c<2;c++){
    aqh[c] = *(const short8*)(Qbh + (size_t)(qrow + fr)*ldq + c*32 + fg*8);
    aql[c] = *(const short8*)(Qbl + (size_t)(qrow + fr)*ldq + c*32 + fg*8);
  }

  f32x4 oacc[4];
#pragma unroll
  for (int j=0;j<4;j++) oacc[j] = (f32x4)0.f;
  float mrun[4] = {-1e30f,-1e30f,-1e30f,-1e30f};
  float lrun[4] = {0.f,0.f,0.f,0.f};
  const float LOG2E = 1.44269504089f;

  const int nkc = (Lk + 31) >> 5;
  for (int kc = 0; kc < nkc; ++kc) {
    const int k0 = kc << 5;
    __syncthreads();
    {
      const int krow = tid >> 3;
      const int dh0  = (tid & 7) << 3;
      int gk = k0 + krow; if (gk > Lk-1) gk = Lk-1;
      short8 kh = *(const short8*)(Kbh + (size_t)gk*ldk + dh0);
      short8 kl = *(const short8*)(Kbl + (size_t)gk*ldk + dh0);
      short8 vh = *(const short8*)(Vbh + (size_t)gk*ldv + dh0);
      short8 vl = *(const short8*)(Vbl + (size_t)gk*ldv + dh0);
      *(short8*)(&sKh[krow][dh0]) = kh;
      *(short8*)(&sKl[krow][dh0]) = kl;
#pragma unroll
      for (int j=0;j<8;j++){
        sVTh[dh0+j][krow] = __builtin_bit_cast(bf16, (short)vh[j]);
        sVTl[dh0+j][krow] = __builtin_bit_cast(bf16, (short)vl[j]);
      }
    }
    __syncthreads();

    f32x4 sfr[2];
#pragma unroll
    for (int nt=0; nt<2; ++nt) {
      f32x4 sacc = (f32x4)0.f;
#pragma unroll
      for (int c=0;c<2;c++) {
        short8 bkh = *(const short8*)(&sKh[nt*16 + fr][c*32 + fg*8]);
        short8 bkl = *(const short8*)(&sKl[nt*16 + fr][c*32 + fg*8]);
        sacc = __builtin_amdgcn_mfma_f32_16x16x32_bf16(aqh[c], bkh, sacc, 0,0,0);
        sacc = __builtin_amdgcn_mfma_f32_16x16x32_bf16(aql[c], bkh, sacc, 0,0,0);
        sacc = __builtin_amdgcn_mfma_f32_16x16x32_bf16(aqh[c], bkl, sacc, 0,0,0);
      }
      sfr[nt] = sacc;
    }

    float pv0[4], pv1[4], mnew[4];
#pragma unroll
    for (int r=0;r<4;r++){
      float s0 = sfr[0][r]*scale, s1 = sfr[1][r]*scale;
      if (MASK) {
        if (k0 + fr      >= Lk) s0 = -1e30f;
        if (k0 + 16 + fr >= Lk) s1 = -1e30f;
      }
      pv0[r] = s0; pv1[r] = s1;
      float mx = fmaxf(s0, s1);
#pragma unroll
      for (int m=1;m<16;m<<=1) mx = fmaxf(mx, __shfl_xor(mx,m,64));
      mnew[r] = fmaxf(mrun[r], mx);
    }
#pragma unroll
    for (int r=0;r<4;r++){
      float sc = exp2f((mrun[r]-mnew[r])*LOG2E);
      mrun[r] = mnew[r];
      float p0 = exp2f((pv0[r]-mnew[r])*LOG2E);
      float p1 = exp2f((pv1[r]-mnew[r])*LOG2E);
      float ladd = p0 + p1;
#pragma unroll
      for (int m=1;m<16;m<<=1) ladd += __shfl_xor(ladd,m,64);
      lrun[r] = lrun[r]*sc + ladd;
#pragma unroll
      for (int j=0;j<4;j++) oacc[j][r] *= sc;
      short h0 = f2b(p0), h1 = f2b(p1);
      sPh[wid][fg*4+r][fr]       = __builtin_bit_cast(bf16, h0);
      sPh[wid][fg*4+r][16 + fr]  = __builtin_bit_cast(bf16, h1);
      sPl[wid][fg*4+r][fr]       = __float2bfloat16(p0 - b2f(h0));
      sPl[wid][fg*4+r][16 + fr]  = __float2bfloat16(p1 - b2f(h1));
    }

    asm volatile("s_waitcnt lgkmcnt(0)" ::: "memory");
    short8 pah = *(const short8*)(&sPh[wid][fr][fg*8]);
    short8 pal = *(const short8*)(&sPl[wid][fr][fg*8]);
#pragma unroll
    for (int ni=0; ni<4; ++ni) {
      short8 bvh = *(const short8*)(&sVTh[ni*16 + fr][fg*8]);
      short8 bvl = *(const short8*)(&sVTl[ni*16 + fr][fg*8]);
      oacc[ni] = __builtin_amdgcn_mfma_f32_16x16x32_bf16(pah, bvh, oacc[ni], 0,0,0);
      oacc[ni] = __builtin_amdgcn_mfma_f32_16x16x32_bf16(pal, bvh, oacc[ni], 0,0,0);
      oacc[ni] = __builtin_amdgcn_mfma_f32_16x16x32_bf16(pah, bvl, oacc[ni], 0,0,0);
    }
  }

  float inv[4];
#pragma unroll
  for (int r=0;r<4;r++) inv[r] = 1.f / lrun[r];
  const size_t orow0 = (size_t)bb*Lq + qt*64 + wid*16;
#pragma unroll
  for (int ni=0; ni<4; ++ni)
#pragma unroll
    for (int r=0;r<4;r++)
      O[(orow0 + fg*4 + r)*ldo + hh*64 + ni*16 + fr] = oacc[ni][r]*inv[r];
}

// ============ f32 GEGLU ============
__global__ __launch_bounds__(256) void p5_gg(const float* __restrict__ P,
                                             float* __restrict__ Gt)
{
  size_t idx = (size_t)blockIdx.x*256 + threadIdx.x;
  size_t m = idx / 512;
  size_t n = (idx % 512) * 4;
  float4 v = *(const float4*)(P + m*4096 + n);
  float4 g = *(const float4*)(P + m*4096 + 2048 + n);
  float ve[4] = {v.x,v.y,v.z,v.w};
  float ge[4] = {g.x,g.y,g.z,g.w};
  float re[4];
#pragma unroll
  for (int j=0;j<4;j++){
    float gel = 0.5f*ge[j]*(1.f + erff(ge[j]*0.70710678118f));
    re[j] = ve[j]*gel;
  }
  *(float4*)(Gt + m*2048 + n) = make_float4(re[0],re[1],re[2],re[3]);
}

// ============ host ============
extern "C" void kernel_launch(void* const* d_in, const int* in_sizes, int n_in,
                              void* d_out, int out_size, void* d_ws, size_t ws_size,
                              hipStream_t stream)
{
  (void)in_sizes; (void)n_in; (void)out_size;
  printf("[tb7] kernel_launch build=r7-mfma-gemm ws=%zu\n", ws_size);

  const float* x    = (const float*)d_in[0];
  const float* ctx  = (const float*)d_in[1];
  const float* ln1g = (const float*)d_in[2];
  const float* ln1b = (const float*)d_in[3];
  const float* ln2g = (const float*)d_in[4];
  const float* ln2b = (const float*)d_in[5];
  const float* ln3g = (const float*)d_in[6];
  const float* ln3b = (const float*)d_in[7];
  const float* wq1  = (const float*)d_in[8];
  const float* wk1  = (const float*)d_in[9];
  const float* wv1  = (const float*)d_in[10];
  const float* wo1  = (const float*)d_in[11];
  const float* bo1  = (const float*)d_in[12];
  const float* wq2  = (const float*)d_in[13];
  const float* wk2  = (const float*)d_in[14];
  const float* wv2  = (const float*)d_in[15];
  const float* wo2  = (const float*)d_in[16];
  const float* bo2  = (const float*)d_in[17];
  const float* w1   = (const float*)d_in[18];
  const float* b1   = (const float*)d_in[19];
  const float* w2   = (const float*)d_in[20];
  const float* b2   = (const float*)d_in[21];
  float* out = (float*)d_out;

  char* ws = (char*)d_ws;
  size_t off = 0;
  auto alloc = [&](size_t bytes)->void* {
    void* p = ws + off; off += (bytes + 255) & ~(size_t)255; return p;
  };
  auto wpair = [&](size_t elems, bf16*& h, bf16*& l){
    h = (bf16*)alloc(elems*2); l = (bf16*)alloc(elems*2);
  };
  bf16 *wq1h,*wq1l; wpair((size_t)512*512,  wq1h, wq1l);
  bf16 *wk1h,*wk1l; wpair((size_t)512*512,  wk1h, wk1l);
  bf16 *wv1h,*wv1l; wpair((size_t)512*512,  wv1h, wv1l);
  bf16 *wo1h,*wo1l; wpair((size_t)512*512,  wo1h, wo1l);
  bf16 *wq2h,*wq2l; wpair((size_t)512*512,  wq2h, wq2l);
  bf16 *wk2h,*wk2l; wpair((size_t)768*512,  wk2h, wk2l);
  bf16 *wv2h,*wv2l; wpair((size_t)768*512,  wv2h, wv2l);
  bf16 *wo2h,*wo2l; wpair((size_t)512*512,  wo2h, wo2l);
  bf16 *w1h, *w1l;  wpair((size_t)512*4096, w1h,  w1l);
  bf16 *w2h, *w2l;  wpair((size_t)2048*512, w2h,  w2l);

  float* h   = (float*)alloc((size_t)8192*512*4);
  float* q1  = (float*)alloc((size_t)8192*512*4);
  float* k1  = (float*)alloc((size_t)8192*512*4);
  float* v1  = (float*)alloc((size_t)8192*512*4);
  float* ob  = (float*)alloc((size_t)8192*512*4);
  float* x1  = (float*)alloc((size_t)8192*512*4);
  float* pch = (float*)alloc((size_t)2048*4096*4);
  float* gch = (float*)alloc((size_t)2048*2048*4);
  bf16 *qh = (bf16*)alloc((size_t)8192*512*2), *ql = (bf16*)alloc((size_t)8192*512*2);
  bf16 *kh = (bf16*)alloc((size_t)8192*512*2), *kl = (bf16*)alloc((size_t)8192*512*2);
  bf16 *vh = (bf16*)alloc((size_t)8192*512*2), *vl = (bf16*)alloc((size_t)8192*512*2);
  float* k2f = (float*)alloc((size_t)616*512*4);
  float* v2f = (float*)alloc((size_t)616*512*4);
  bf16 *k2h = (bf16*)alloc((size_t)616*512*2), *k2l = (bf16*)alloc((size_t)616*512*2);
  bf16 *v2h = (bf16*)alloc((size_t)616*512*2), *v2l = (bf16*)alloc((size_t)616*512*2);

  dim3 blk(256);

  // ---- weight pre-split (flat, layout preserved [K][N]) ----
  tb_split<<<dim3(256),  blk, 0, stream>>>(wq1, wq1h, wq1l, 512*512/4);
  tb_split<<<dim3(256),  blk, 0, stream>>>(wk1, wk1h, wk1l, 512*512/4);
  tb_split<<<dim3(256),  blk, 0, stream>>>(wv1, wv1h, wv1l, 512*512/4);
  tb_split<<<dim3(256),  blk, 0, stream>>>(wo1, wo1h, wo1l, 512*512/4);
  tb_split<<<dim3(256),  blk, 0, stream>>>(wq2, wq2h, wq2l, 512*512/4);
  tb_split<<<dim3(384),  blk, 0, stream>>>(wk2, wk2h, wk2l, 768*512/4);
  tb_split<<<dim3(384),  blk, 0, stream>>>(wv2, wv2h, wv2l, 768*512/4);
  tb_split<<<dim3(256),  blk, 0, stream>>>(wo2, wo2h, wo2l, 512*512/4);
  tb_split<<<dim3(2048), blk, 0, stream>>>(w1,  w1h,  w1l,  512*4096/4);
  tb_split<<<dim3(1024), blk, 0, stream>>>(w2,  w2h,  w2l,  2048*512/4);

  // ---- self attention ----
  p5_ln<<<dim3(2048), blk, 0, stream>>>(x, ln1g, ln1b, h);
  mm7<false,false><<<dim3(64*4), blk, 0, stream>>>(h, wq1h, wq1l, nullptr, nullptr, q1, 8192, 512, 512);
  mm7<false,false><<<dim3(64*4), blk, 0, stream>>>(h, wk1h, wk1l, nullptr, nullptr, k1, 8192, 512, 512);
  mm7<false,false><<<dim3(64*4), blk, 0, stream>>>(h, wv1h, wv1l, nullptr, nullptr, v1, 8192, 512, 512);
  tb_split<<<dim3(4096), blk, 0, stream>>>(q1, qh, ql, 8192*512/4);
  tb_split<<<dim3(4096), blk, 0, stream>>>(k1, kh, kl, 8192*512/4);
  tb_split<<<dim3(4096), blk, 0, stream>>>(v1, vh, vl, 8192*512/4);
  tb_fa<false><<<dim3(1024), blk, 0, stream>>>(qh, ql, 512, kh, kl, 512, vh, vl, 512,
                                               ob, 512, 1024, 1024, 0.125f);
  mm7<true,true><<<dim3(64*4), blk, 0, stream>>>(ob, wo1h, wo1l, bo1, x, x1, 8192, 512, 512);

  // ---- cross attention ----
  p5_ln<<<dim3(2048), blk, 0, stream>>>(x1, ln2g, ln2b, h);
  mm7<false,false><<<dim3(64*4), blk, 0, stream>>>(h, wq2h, wq2l, nullptr, nullptr, q1, 8192, 512, 512);
  mm7<false,false><<<dim3(5*4), blk, 0, stream>>>(ctx, wk2h, wk2l, nullptr, nullptr, k2f, 616, 512, 768);
  mm7<false,false><<<dim3(5*4), blk, 0, stream>>>(ctx, wv2h, wv2l, nullptr, nullptr, v2f, 616, 512, 768);
  tb_split<<<dim3(4096), blk, 0, stream>>>(q1, qh, ql, 8192*512/4);
  tb_split<<<dim3(308), blk, 0, stream>>>(k2f, k2h, k2l, 616*512/4);
  tb_split<<<dim3(308), blk, 0, stream>>>(v2f, v2h, v2l, 616*512/4);
  tb_fa<true><<<dim3(1024), blk, 0, stream>>>(qh, ql, 512, k2h, k2l, 512, v2h, v2l, 512,
                                              ob, 512, 1024, 77, 0.125f);
  mm7<true,true><<<dim3(64*4), blk, 0, stream>>>(ob, wo2h, wo2l, bo2, x1, out, 8192, 512, 512);

  // ---- feed-forward (GEGLU), 4 chunks of 2048 rows ----
  p5_ln<<<dim3(2048), blk, 0, stream>>>(out, ln3g, ln3b, h);
  for (int c = 0; c < 4; ++c) {
    const size_t r0 = (size_t)c*2048;
    mm7<true,false><<<dim3(16*32), blk, 0, stream>>>(h + r0*512, w1h, w1l, b1, nullptr, pch, 2048, 4096, 512);
    p5_gg<<<dim3(4096), blk, 0, stream>>>(pch, gch);
    mm7<true,true><<<dim3(16*4), blk, 0, stream>>>(gch, w2h, w2l, b2, out + r0*512, out + r0*512, 2048, 512, 2048);
  }
}

// Round 9
// 1079.781 us; speedup vs baseline: 4.7106x; 1.8098x over previous
//
// tb9 — round-8 resubmit after infra failure (fused splits, un-chunked FF, padded LDS)
#include <hip/hip_runtime.h>
#include <hip/hip_bf16.h>
#include <cstdio>

using bf16 = __hip_bfloat16;
typedef __attribute__((ext_vector_type(8))) short short8;
typedef __attribute__((ext_vector_type(4))) short short4v;
typedef __attribute__((ext_vector_type(4))) float f32x4;

#define DEV __device__ __forceinline__

DEV short f2b(float x){ __hip_bfloat16 h = __float2bfloat16(x); return __builtin_bit_cast(short, h); }
DEV float b2f(short s){ __hip_bfloat16 h = __builtin_bit_cast(__hip_bfloat16, s); return __bfloat162float(h); }

// ============ f32 LayerNorm, rows of 512 ============
__global__ __launch_bounds__(256) void p5_ln(const float* __restrict__ X,
                                             const float* __restrict__ G,
                                             const float* __restrict__ Bt,
                                             float* __restrict__ O)
{
  const int wid = threadIdx.x >> 6, lane = threadIdx.x & 63;
  const int row = blockIdx.x*4 + wid;
  const float* xr = X + (size_t)row*512 + lane*8;
  float4 v0 = *(const float4*)xr;
  float4 v1 = *(const float4*)(xr+4);
  float xe[8] = {v0.x,v0.y,v0.z,v0.w,v1.x,v1.y,v1.z,v1.w};
  float s = 0.f, sq = 0.f;
#pragma unroll
  for (int j=0;j<8;j++){ s += xe[j]; sq += xe[j]*xe[j]; }
#pragma unroll
  for (int m=1;m<64;m<<=1){ s += __shfl_xor(s,m,64); sq += __shfl_xor(sq,m,64); }
  const float mean = s * (1.f/512.f);
  const float var  = sq * (1.f/512.f) - mean*mean;
  const float rs = rsqrtf(var + 1e-5f);
  float oe[8];
#pragma unroll
  for (int j=0;j<8;j++){
    int c = lane*8 + j;
    oe[j] = (xe[j]-mean)*rs*G[c] + Bt[c];
  }
  float* orow = O + (size_t)row*512 + lane*8;
  *(float4*)orow     = make_float4(oe[0],oe[1],oe[2],oe[3]);
  *(float4*)(orow+4) = make_float4(oe[4],oe[5],oe[6],oe[7]);
}

// ============ f32 -> bf16 hi/lo, flat (weights only) ============
__global__ __launch_bounds__(256) void tb_split(const float* __restrict__ in,
                                                bf16* __restrict__ oh,
                                                bf16* __restrict__ ol, int n4)
{
  int i = blockIdx.x*256 + threadIdx.x;
  if (i >= n4) return;
  float4 v = ((const float4*)in)[i];
  float e[4] = {v.x, v.y, v.z, v.w};
  short4v sh, sl;
#pragma unroll
  for (int j=0;j<4;j++){
    short h = f2b(e[j]);
    sh[j] = h;
    sl[j] = f2b(e[j] - b2f(h));
  }
  ((short4v*)oh)[i] = sh;
  ((short4v*)ol)[i] = sl;
}

// ============ GEGLU hi/lo in place (rows of 4096, val -> cols 0..2047) ============
__global__ __launch_bounds__(256) void tb_gg(bf16* __restrict__ Ph, bf16* __restrict__ Pl)
{
  size_t m = blockIdx.x;
  size_t n = (size_t)threadIdx.x << 3;
  bf16* vph = Ph + m*4096 + n;
  bf16* vpl = Pl + m*4096 + n;
  short8 vh = *(const short8*)vph;
  short8 vl = *(const short8*)vpl;
  short8 gh = *(const short8*)(Ph + m*4096 + 2048 + n);
  short8 gl = *(const short8*)(Pl + m*4096 + 2048 + n);
  short8 rh, rl;
#pragma unroll
  for (int j=0;j<8;j++){
    float gv = b2f(gh[j]) + b2f(gl[j]);
    float vv = b2f(vh[j]) + b2f(vl[j]);
    float gel = 0.5f*gv*(1.f + erff(gv*0.70710678118f));
    float val = vv*gel;
    short h = f2b(val);
    rh[j] = h;
    rl[j] = f2b(val - b2f(h));
  }
  *(short8*)vph = rh;
  *(short8*)vpl = rl;
}

// ============ MFMA hi/lo GEMM ============
// AMODE 0: A f32 (split in-kernel). AMODE 1: A = bf16 hi/lo pair.
template<int AMODE, bool BIAS, bool RES, bool OUTF, bool OUTP>
__global__ __launch_bounds__(256) void mm8(
    const void* __restrict__ A0, const void* __restrict__ A1, int lda,
    const bf16* __restrict__ Wh, const bf16* __restrict__ Wl,
    const float* __restrict__ bias,
    const float* __restrict__ res, int ldres,
    float* __restrict__ Cf, int ldc,
    bf16* __restrict__ Ch, bf16* __restrict__ Cl, int ldcp,
    int M, int N, int K)
{
  __shared__ bf16 sAh[128][44];
  __shared__ bf16 sAl[128][44];
  __shared__ bf16 sBh[128][44];   // [n][k]
  __shared__ bf16 sBl[128][44];
  const int tid = threadIdx.x, lane = tid & 63;
  const int nbn = N >> 7;
  const int m0 = (blockIdx.x / nbn) << 7;
  const int n0 = (blockIdx.x % nbn) << 7;
  const int wid = tid >> 6;
  const int wr = (wid >> 1) << 6, wc = (wid & 1) << 6;
  const int fr = lane & 15, fgk = (lane >> 4) << 3;

  f32x4 acc[4][4];
#pragma unroll
  for (int i=0;i<4;i++)
#pragma unroll
    for (int j=0;j<4;j++) acc[i][j] = (f32x4)0.f;

  for (int k0 = 0; k0 < K; k0 += 32) {
    __syncthreads();
    if (AMODE == 0) {
      const float* A = (const float*)A0;
#pragma unroll
      for (int i = 0; i < 4; ++i) {
        const int li = i*256 + tid;
        const int row = li >> 3;
        const int kc  = (li & 7) << 2;
        int ga = m0 + row; if (ga >= M) ga = M - 1;
        float4 av = *(const float4*)(A + (size_t)ga*lda + k0 + kc);
        float e[4] = {av.x, av.y, av.z, av.w};
        short4v sh, sl;
#pragma unroll
        for (int j=0;j<4;j++){
          short h = f2b(e[j]);
          sh[j] = h;
          sl[j] = f2b(e[j] - b2f(h));
        }
        *(short4v*)(&sAh[row][kc]) = sh;
        *(short4v*)(&sAl[row][kc]) = sl;
      }
    } else {
      const bf16* Ah = (const bf16*)A0;
      const bf16* Al = (const bf16*)A1;
#pragma unroll
      for (int i = 0; i < 2; ++i) {
        const int li = i*256 + tid;
        const int row = li >> 2;
        const int kc  = (li & 3) << 3;
        int ga = m0 + row; if (ga >= M) ga = M - 1;
        const size_t goff = (size_t)ga*lda + k0 + kc;
        *(short8*)(&sAh[row][kc]) = *(const short8*)(Ah + goff);
        *(short8*)(&sAl[row][kc]) = *(const short8*)(Al + goff);
      }
    }
#pragma unroll
    for (int i = 0; i < 2; ++i) {
      const int li = i*256 + tid;
      const int kr = li >> 4;
      const int nc = (li & 15) << 3;
      const size_t goff = (size_t)(k0 + kr)*N + n0 + nc;
      short8 bh = *(const short8*)(Wh + goff);
      short8 bl = *(const short8*)(Wl + goff);
#pragma unroll
      for (int j=0;j<8;j++){
        sBh[nc+j][kr] = __builtin_bit_cast(bf16, (short)bh[j]);
        sBl[nc+j][kr] = __builtin_bit_cast(bf16, (short)bl[j]);
      }
    }
    __syncthreads();

    short8 avh[4], avl[4], bvh[4], bvl[4];
#pragma unroll
    for (int i=0;i<4;i++) {
      avh[i] = *(const short8*)(&sAh[wr + i*16 + fr][fgk]);
      avl[i] = *(const short8*)(&sAl[wr + i*16 + fr][fgk]);
    }
#pragma unroll
    for (int j=0;j<4;j++) {
      bvh[j] = *(const short8*)(&sBh[wc + j*16 + fr][fgk]);
      bvl[j] = *(const short8*)(&sBl[wc + j*16 + fr][fgk]);
    }
#pragma unroll
    for (int i=0;i<4;i++)
#pragma unroll
      for (int j=0;j<4;j++) {
        acc[i][j] = __builtin_amdgcn_mfma_f32_16x16x32_bf16(avh[i], bvh[j], acc[i][j], 0,0,0);
        acc[i][j] = __builtin_amdgcn_mfma_f32_16x16x32_bf16(avl[i], bvh[j], acc[i][j], 0,0,0);
        acc[i][j] = __builtin_amdgcn_mfma_f32_16x16x32_bf16(avh[i], bvl[j], acc[i][j], 0,0,0);
      }
  }

  const int cr0 = (lane >> 4) << 2, cc = lane & 15;
#pragma unroll
  for (int i=0;i<4;i++) {
#pragma unroll
    for (int r=0;r<4;r++) {
      const int grow = m0 + wr + i*16 + cr0 + r;
      if (grow >= M) continue;
#pragma unroll
      for (int j=0;j<4;j++) {
        const int gcol = n0 + wc + j*16 + cc;
        float v = acc[i][j][r];
        if (BIAS) v += bias[gcol];
        if (RES)  v += res[(size_t)grow*ldres + gcol];
        if (OUTF) Cf[(size_t)grow*ldc + gcol] = v;
        if (OUTP) {
          short h = f2b(v);
          const size_t pidx = (size_t)grow*ldcp + gcol;
          Ch[pidx] = __builtin_bit_cast(bf16, h);
          Cl[pidx] = __float2bfloat16(v - b2f(h));
        }
      }
    }
  }
}

// ============ MFMA flash attention, hi/lo operands, f32 output ============
template<bool MASK>
__global__ __launch_bounds__(256) void tb_fa(
    const bf16* __restrict__ Qh, const bf16* __restrict__ Ql, int ldq,
    const bf16* __restrict__ Kh, const bf16* __restrict__ Kl, int ldk,
    const bf16* __restrict__ Vh, const bf16* __restrict__ Vl, int ldv,
    float* __restrict__ O, int ldo,
    int Lq, int Lk, float scale)
{
  __shared__ bf16 sKh[32][72];
  __shared__ bf16 sKl[32][72];
  __shared__ bf16 sVTh[64][40];
  __shared__ bf16 sVTl[64][40];
  __shared__ bf16 sPh[4][16][48];
  __shared__ bf16 sPl[4][16][48];
  const int tid = threadIdx.x, lane = tid & 63, wid = tid >> 6;
  const int nq = Lq >> 6;
  int bid = blockIdx.x;
  const int qt = bid % nq; bid /= nq;
  const int hh = bid & 7; const int bb = bid >> 3;

  const bf16* Qbh = Qh + (size_t)bb*Lq*ldq + hh*64;
  const bf16* Qbl = Ql + (size_t)bb*Lq*ldq + hh*64;
  const bf16* Kbh = Kh + (size_t)bb*Lk*ldk + hh*64;
  const bf16* Kbl = Kl + (size_t)bb*Lk*ldk + hh*64;
  const bf16* Vbh = Vh + (size_t)bb*Lk*ldv + hh*64;
  const bf16* Vbl = Vl + (size_t)bb*Lk*ldv + hh*64;

  const int qrow = qt*64 + wid*16;
  const int fr = lane & 15, fg = lane >> 4;

  short8 aqh[2], aql[2];
#pragma unroll
  for (int c=0;c<2;c++){
    aqh[c] = *(const short8*)(Qbh + (size_t)(qrow + fr)*ldq + c*32 + fg*8);
    aql[c] = *(const short8*)(Qbl + (size_t)(qrow + fr)*ldq + c*32 + fg*8);
  }

  f32x4 oacc[4];
#pragma unroll
  for (int j=0;j<4;j++) oacc[j] = (f32x4)0.f;
  float mrun[4] = {-1e30f,-1e30f,-1e30f,-1e30f};
  float lrun[4] = {0.f,0.f,0.f,0.f};
  const float LOG2E = 1.44269504089f;

  const int nkc = (Lk + 31) >> 5;
  for (int kc = 0; kc < nkc; ++kc) {
    const int k0 = kc << 5;
    __syncthreads();
    {
      const int krow = tid >> 3;
      const int dh0  = (tid & 7) << 3;
      int gk = k0 + krow; if (gk > Lk-1) gk = Lk-1;
      short8 kh = *(const short8*)(Kbh + (size_t)gk*ldk + dh0);
      short8 kl = *(const short8*)(Kbl + (size_t)gk*ldk + dh0);
      short8 vh = *(const short8*)(Vbh + (size_t)gk*ldv + dh0);
      short8 vl = *(const short8*)(Vbl + (size_t)gk*ldv + dh0);
      *(short8*)(&sKh[krow][dh0]) = kh;
      *(short8*)(&sKl[krow][dh0]) = kl;
#pragma unroll
      for (int j=0;j<8;j++){
        sVTh[dh0+j][krow] = __builtin_bit_cast(bf16, (short)vh[j]);
        sVTl[dh0+j][krow] = __builtin_bit_cast(bf16, (short)vl[j]);
      }
    }
    __syncthreads();

    f32x4 sfr[2];
#pragma unroll
    for (int nt=0; nt<2; ++nt) {
      f32x4 sacc = (f32x4)0.f;
#pragma unroll
      for (int c=0;c<2;c++) {
        short8 bkh = *(const short8*)(&sKh[nt*16 + fr][c*32 + fg*8]);
        short8 bkl = *(const short8*)(&sKl[nt*16 + fr][c*32 + fg*8]);
        sacc = __builtin_amdgcn_mfma_f32_16x16x32_bf16(aqh[c], bkh, sacc, 0,0,0);
        sacc = __builtin_amdgcn_mfma_f32_16x16x32_bf16(aql[c], bkh, sacc, 0,0,0);
        sacc = __builtin_amdgcn_mfma_f32_16x16x32_bf16(aqh[c], bkl, sacc, 0,0,0);
      }
      sfr[nt] = sacc;
    }

    float pv0[4], pv1[4], mnew[4];
#pragma unroll
    for (int r=0;r<4;r++){
      float s0 = sfr[0][r]*scale, s1 = sfr[1][r]*scale;
      if (MASK) {
        if (k0 + fr      >= Lk) s0 = -1e30f;
        if (k0 + 16 + fr >= Lk) s1 = -1e30f;
      }
      pv0[r] = s0; pv1[r] = s1;
      float mx = fmaxf(s0, s1);
#pragma unroll
      for (int m=1;m<16;m<<=1) mx = fmaxf(mx, __shfl_xor(mx,m,64));
      mnew[r] = fmaxf(mrun[r], mx);
    }
#pragma unroll
    for (int r=0;r<4;r++){
      float sc = exp2f((mrun[r]-mnew[r])*LOG2E);
      mrun[r] = mnew[r];
      float p0 = exp2f((pv0[r]-mnew[r])*LOG2E);
      float p1 = exp2f((pv1[r]-mnew[r])*LOG2E);
      float ladd = p0 + p1;
#pragma unroll
      for (int m=1;m<16;m<<=1) ladd += __shfl_xor(ladd,m,64);
      lrun[r] = lrun[r]*sc + ladd;
#pragma unroll
      for (int j=0;j<4;j++) oacc[j][r] *= sc;
      short h0 = f2b(p0), h1 = f2b(p1);
      sPh[wid][fg*4+r][fr]       = __builtin_bit_cast(bf16, h0);
      sPh[wid][fg*4+r][16 + fr]  = __builtin_bit_cast(bf16, h1);
      sPl[wid][fg*4+r][fr]       = __float2bfloat16(p0 - b2f(h0));
      sPl[wid][fg*4+r][16 + fr]  = __float2bfloat16(p1 - b2f(h1));
    }

    asm volatile("s_waitcnt lgkmcnt(0)" ::: "memory");
    short8 pah = *(const short8*)(&sPh[wid][fr][fg*8]);
    short8 pal = *(const short8*)(&sPl[wid][fr][fg*8]);
#pragma unroll
    for (int ni=0; ni<4; ++ni) {
      short8 bvh = *(const short8*)(&sVTh[ni*16 + fr][fg*8]);
      short8 bvl = *(const short8*)(&sVTl[ni*16 + fr][fg*8]);
      oacc[ni] = __builtin_amdgcn_mfma_f32_16x16x32_bf16(pah, bvh, oacc[ni], 0,0,0);
      oacc[ni] = __builtin_amdgcn_mfma_f32_16x16x32_bf16(pal, bvh, oacc[ni], 0,0,0);
      oacc[ni] = __builtin_amdgcn_mfma_f32_16x16x32_bf16(pah, bvl, oacc[ni], 0,0,0);
    }
  }

  float inv[4];
#pragma unroll
  for (int r=0;r<4;r++) inv[r] = 1.f / lrun[r];
  const size_t orow0 = (size_t)bb*Lq + qt*64 + wid*16;
#pragma unroll
  for (int ni=0; ni<4; ++ni)
#pragma unroll
    for (int r=0;r<4;r++)
      O[(orow0 + fg*4 + r)*ldo + hh*64 + ni*16 + fr] = oacc[ni][r]*inv[r];
}

// ============ host ============
extern "C" void kernel_launch(void* const* d_in, const int* in_sizes, int n_in,
                              void* d_out, int out_size, void* d_ws, size_t ws_size,
                              hipStream_t stream)
{
  (void)in_sizes; (void)n_in; (void)out_size;
  printf("[tb9] build=r9-resubmit ws=%zu\n", ws_size);

  const float* x    = (const float*)d_in[0];
  const float* ctx  = (const float*)d_in[1];
  const float* ln1g = (const float*)d_in[2];
  const float* ln1b = (const float*)d_in[3];
  const float* ln2g = (const float*)d_in[4];
  const float* ln2b = (const float*)d_in[5];
  const float* ln3g = (const float*)d_in[6];
  const float* ln3b = (const float*)d_in[7];
  const float* wq1  = (const float*)d_in[8];
  const float* wk1  = (const float*)d_in[9];
  const float* wv1  = (const float*)d_in[10];
  const float* wo1  = (const float*)d_in[11];
  const float* bo1  = (const float*)d_in[12];
  const float* wq2  = (const float*)d_in[13];
  const float* wk2  = (const float*)d_in[14];
  const float* wv2  = (const float*)d_in[15];
  const float* wo2  = (const float*)d_in[16];
  const float* bo2  = (const float*)d_in[17];
  const float* w1   = (const float*)d_in[18];
  const float* b1   = (const float*)d_in[19];
  const float* w2   = (const float*)d_in[20];
  const float* b2   = (const float*)d_in[21];
  float* out = (float*)d_out;

  char* ws = (char*)d_ws;
  size_t off = 0;
  auto alloc = [&](size_t bytes)->void* {
    void* p = ws + off; off += (bytes + 255) & ~(size_t)255; return p;
  };
  auto wpair = [&](size_t elems, bf16*& h, bf16*& l){
    h = (bf16*)alloc(elems*2); l = (bf16*)alloc(elems*2);
  };
  bf16 *wq1h,*wq1l; wpair((size_t)512*512,  wq1h, wq1l);
  bf16 *wk1h,*wk1l; wpair((size_t)512*512,  wk1h, wk1l);
  bf16 *wv1h,*wv1l; wpair((size_t)512*512,  wv1h, wv1l);
  bf16 *wo1h,*wo1l; wpair((size_t)512*512,  wo1h, wo1l);
  bf16 *wq2h,*wq2l; wpair((size_t)512*512,  wq2h, wq2l);
  bf16 *wk2h,*wk2l; wpair((size_t)768*512,  wk2h, wk2l);
  bf16 *wv2h,*wv2l; wpair((size_t)768*512,  wv2h, wv2l);
  bf16 *wo2h,*wo2l; wpair((size_t)512*512,  wo2h, wo2l);
  bf16 *w1h, *w1l;  wpair((size_t)512*4096, w1h,  w1l);
  bf16 *w2h, *w2l;  wpair((size_t)2048*512, w2h,  w2l);

  float* h   = (float*)alloc((size_t)8192*512*4);
  float* x1  = (float*)alloc((size_t)8192*512*4);
  float* ob  = (float*)alloc((size_t)8192*512*4);

  char* U = (char*)alloc((size_t)134217728);
  const size_t SZ = (size_t)8192*512*2;
  bf16* qh = (bf16*)(U);        bf16* ql = (bf16*)(U + SZ);
  bf16* kh = (bf16*)(U + 2*SZ); bf16* kl = (bf16*)(U + 3*SZ);
  bf16* vh = (bf16*)(U + 4*SZ); bf16* vl = (bf16*)(U + 5*SZ);
  bf16* k2h = (bf16*)(U + 2*SZ);                 bf16* k2l = (bf16*)(U + 2*SZ + 1261568);
  bf16* v2h = (bf16*)(U + 2*SZ + 2*1261568);     bf16* v2l = (bf16*)(U + 2*SZ + 3*1261568);
  bf16* pbh = (bf16*)(U);       bf16* pbl = (bf16*)(U + (size_t)8192*4096*2);

  dim3 blk(256);

  tb_split<<<dim3(256),  blk, 0, stream>>>(wq1, wq1h, wq1l, 512*512/4);
  tb_split<<<dim3(256),  blk, 0, stream>>>(wk1, wk1h, wk1l, 512*512/4);
  tb_split<<<dim3(256),  blk, 0, stream>>>(wv1, wv1h, wv1l, 512*512/4);
  tb_split<<<dim3(256),  blk, 0, stream>>>(wo1, wo1h, wo1l, 512*512/4);
  tb_split<<<dim3(256),  blk, 0, stream>>>(wq2, wq2h, wq2l, 512*512/4);
  tb_split<<<dim3(384),  blk, 0, stream>>>(wk2, wk2h, wk2l, 768*512/4);
  tb_split<<<dim3(384),  blk, 0, stream>>>(wv2, wv2h, wv2l, 768*512/4);
  tb_split<<<dim3(256),  blk, 0, stream>>>(wo2, wo2h, wo2l, 512*512/4);
  tb_split<<<dim3(2048), blk, 0, stream>>>(w1,  w1h,  w1l,  512*4096/4);
  tb_split<<<dim3(1024), blk, 0, stream>>>(w2,  w2h,  w2l,  2048*512/4);

  // ---- self attention ----
  p5_ln<<<dim3(2048), blk, 0, stream>>>(x, ln1g, ln1b, h);
  mm8<0,false,false,false,true><<<dim3(64*4), blk, 0, stream>>>(
      h, nullptr, 512, wq1h, wq1l, nullptr, nullptr, 0,
      nullptr, 0, qh, ql, 512, 8192, 512, 512);
  mm8<0,false,false,false,true><<<dim3(64*4), blk, 0, stream>>>(
      h, nullptr, 512, wk1h, wk1l, nullptr, nullptr, 0,
      nullptr, 0, kh, kl, 512, 8192, 512, 512);
  mm8<0,false,false,false,true><<<dim3(64*4), blk, 0, stream>>>(
      h, nullptr, 512, wv1h, wv1l, nullptr, nullptr, 0,
      nullptr, 0, vh, vl, 512, 8192, 512, 512);
  tb_fa<false><<<dim3(1024), blk, 0, stream>>>(qh, ql, 512, kh, kl, 512, vh, vl, 512,
                                               ob, 512, 1024, 1024, 0.125f);
  mm8<0,true,true,true,false><<<dim3(64*4), blk, 0, stream>>>(
      ob, nullptr, 512, wo1h, wo1l, bo1, x, 512,
      x1, 512, nullptr, nullptr, 0, 8192, 512, 512);

  // ---- cross attention ----
  p5_ln<<<dim3(2048), blk, 0, stream>>>(x1, ln2g, ln2b, h);
  mm8<0,false,false,false,true><<<dim3(64*4), blk, 0, stream>>>(
      h, nullptr, 512, wq2h, wq2l, nullptr, nullptr, 0,
      nullptr, 0, qh, ql, 512, 8192, 512, 512);
  mm8<0,false,false,false,true><<<dim3(5*4), blk, 0, stream>>>(
      ctx, nullptr, 768, wk2h, wk2l, nullptr, nullptr, 0,
      nullptr, 0, k2h, k2l, 512, 616, 512, 768);
  mm8<0,false,false,false,true><<<dim3(5*4), blk, 0, stream>>>(
      ctx, nullptr, 768, wv2h, wv2l, nullptr, nullptr, 0,
      nullptr, 0, v2h, v2l, 512, 616, 512, 768);
  tb_fa<true><<<dim3(1024), blk, 0, stream>>>(qh, ql, 512, k2h, k2l, 512, v2h, v2l, 512,
                                              ob, 512, 1024, 77, 0.125f);
  mm8<0,true,true,true,false><<<dim3(64*4), blk, 0, stream>>>(
      ob, nullptr, 512, wo2h, wo2l, bo2, x1, 512,
      out, 512, nullptr, nullptr, 0, 8192, 512, 512);

  // ---- feed-forward (GEGLU), full width ----
  p5_ln<<<dim3(2048), blk, 0, stream>>>(out, ln3g, ln3b, h);
  mm8<0,true,false,false,true><<<dim3(64*32), blk, 0, stream>>>(
      h, nullptr, 512, w1h, w1l, b1, nullptr, 0,
      nullptr, 0, pbh, pbl, 4096, 8192, 4096, 512);
  tb_gg<<<dim3(8192), blk, 0, stream>>>(pbh, pbl);
  mm8<1,true,true,true,false><<<dim3(64*4), blk, 0, stream>>>(
      pbh, pbl, 4096, w2h, w2l, b2, out, 512,
      out, 512, nullptr, nullptr, 0, 8192, 512, 2048);
}

// Round 11
// 897.465 us; speedup vs baseline: 5.6675x; 1.2031x over previous
//
// tb11 — bisect: round-9 pipeline + wtrans/linear-B only (no fusion) (round 11)
#include <hip/hip_runtime.h>
#include <hip/hip_bf16.h>
#include <cstdio>

using bf16 = __hip_bfloat16;
typedef __attribute__((ext_vector_type(8))) short short8;
typedef __attribute__((ext_vector_type(4))) short short4v;
typedef __attribute__((ext_vector_type(4))) float f32x4;

#define DEV __device__ __forceinline__

DEV short f2b(float x){ __hip_bfloat16 h = __float2bfloat16(x); return __builtin_bit_cast(short, h); }
DEV float b2f(short s){ __hip_bfloat16 h = __builtin_bit_cast(__hip_bfloat16, s); return __bfloat162float(h); }

// ============ weight transpose+split: f32 W[K][N] -> bf16 hi/lo WT[N][K] ============
__global__ __launch_bounds__(256) void wtrans(const float* __restrict__ W,
                                              bf16* __restrict__ Th,
                                              bf16* __restrict__ Tl, int K, int N)
{
  __shared__ float t[32][33];
  const int nbx = N >> 5;
  const int n0 = (blockIdx.x % nbx) << 5;
  const int k0 = (blockIdx.x / nbx) << 5;
  const int tx = threadIdx.x & 31, ty = threadIdx.x >> 5;
#pragma unroll
  for (int it = 0; it < 4; ++it)
    t[ty + it*8][tx] = W[(size_t)(k0 + ty + it*8)*N + n0 + tx];
  __syncthreads();
#pragma unroll
  for (int it = 0; it < 4; ++it) {
    const int nn = ty + it*8;
    float v = t[tx][nn];                 // = W[k0+tx][n0+nn]
    short h = f2b(v);
    size_t idx = (size_t)(n0 + nn)*K + k0 + tx;
    Th[idx] = __builtin_bit_cast(bf16, h);
    Tl[idx] = __float2bfloat16(v - b2f(h));
  }
}

// ============ f32 LayerNorm, rows of 512 ============
__global__ __launch_bounds__(256) void p5_ln(const float* __restrict__ X,
                                             const float* __restrict__ G,
                                             const float* __restrict__ Bt,
                                             float* __restrict__ O)
{
  const int wid = threadIdx.x >> 6, lane = threadIdx.x & 63;
  const int row = blockIdx.x*4 + wid;
  const float* xr = X + (size_t)row*512 + lane*8;
  float4 v0 = *(const float4*)xr;
  float4 v1 = *(const float4*)(xr+4);
  float xe[8] = {v0.x,v0.y,v0.z,v0.w,v1.x,v1.y,v1.z,v1.w};
  float s = 0.f, sq = 0.f;
#pragma unroll
  for (int j=0;j<8;j++){ s += xe[j]; sq += xe[j]*xe[j]; }
#pragma unroll
  for (int m=1;m<64;m<<=1){ s += __shfl_xor(s,m,64); sq += __shfl_xor(sq,m,64); }
  const float mean = s * (1.f/512.f);
  const float var  = sq * (1.f/512.f) - mean*mean;
  const float rs = rsqrtf(var + 1e-5f);
  float oe[8];
#pragma unroll
  for (int j=0;j<8;j++){
    int c = lane*8 + j;
    oe[j] = (xe[j]-mean)*rs*G[c] + Bt[c];
  }
  float* orow = O + (size_t)row*512 + lane*8;
  *(float4*)orow     = make_float4(oe[0],oe[1],oe[2],oe[3]);
  *(float4*)(orow+4) = make_float4(oe[4],oe[5],oe[6],oe[7]);
}

// ============ GEGLU hi/lo in place (rows of 4096, val -> cols 0..2047) ============
__global__ __launch_bounds__(256) void tb_gg(bf16* __restrict__ Ph, bf16* __restrict__ Pl)
{
  size_t m = blockIdx.x;
  size_t n = (size_t)threadIdx.x << 3;
  bf16* vph = Ph + m*4096 + n;
  bf16* vpl = Pl + m*4096 + n;
  short8 vh = *(const short8*)vph;
  short8 vl = *(const short8*)vpl;
  short8 gh = *(const short8*)(Ph + m*4096 + 2048 + n);
  short8 gl = *(const short8*)(Pl + m*4096 + 2048 + n);
  short8 rh, rl;
#pragma unroll
  for (int j=0;j<8;j++){
    float gv = b2f(gh[j]) + b2f(gl[j]);
    float vv = b2f(vh[j]) + b2f(vl[j]);
    float gel = 0.5f*gv*(1.f + erff(gv*0.70710678118f));
    float val = vv*gel;
    short h = f2b(val);
    rh[j] = h;
    rl[j] = f2b(val - b2f(h));
  }
  *(short8*)vph = rh;
  *(short8*)vpl = rl;
}

// ============ MFMA hi/lo GEMM — round-9 structure, linear B from WT[N][K] ============
// AMODE 0: A f32 (split in-kernel). AMODE 1: A = bf16 hi/lo pair.
template<int AMODE, bool BIAS, bool RES, bool OUTF, bool OUTP>
__global__ __launch_bounds__(256) void mm11(
    const void* __restrict__ A0, const void* __restrict__ A1, int lda,
    const bf16* __restrict__ WTh, const bf16* __restrict__ WTl,  // [N][K]
    const float* __restrict__ bias,
    const float* __restrict__ res, int ldres,
    float* __restrict__ Cf, int ldc,
    bf16* __restrict__ Ch, bf16* __restrict__ Cl, int ldcp,
    int M, int N, int K)
{
  __shared__ bf16 sAh[128][44];
  __shared__ bf16 sAl[128][44];
  __shared__ bf16 sBh[128][44];   // [n][k]
  __shared__ bf16 sBl[128][44];
  const int tid = threadIdx.x, lane = tid & 63;
  const int nbn = N >> 7;
  const int m0 = (blockIdx.x / nbn) << 7;
  const int n0 = (blockIdx.x % nbn) << 7;
  const int wid = tid >> 6;
  const int wr = (wid >> 1) << 6, wc = (wid & 1) << 6;
  const int fr = lane & 15, fgk = (lane >> 4) << 3;

  f32x4 acc[4][4];
#pragma unroll
  for (int i=0;i<4;i++)
#pragma unroll
    for (int j=0;j<4;j++) acc[i][j] = (f32x4)0.f;

  for (int k0 = 0; k0 < K; k0 += 32) {
    __syncthreads();
    // ---- stage A (round-9 identical) ----
    if (AMODE == 0) {
      const float* A = (const float*)A0;
#pragma unroll
      for (int i = 0; i < 4; ++i) {
        const int li = i*256 + tid;
        const int row = li >> 3;
        const int kc  = (li & 7) << 2;
        int ga = m0 + row; if (ga >= M) ga = M - 1;
        float4 av = *(const float4*)(A + (size_t)ga*lda + k0 + kc);
        float e[4] = {av.x, av.y, av.z, av.w};
        short4v sh, sl;
#pragma unroll
        for (int j=0;j<4;j++){
          short h = f2b(e[j]);
          sh[j] = h;
          sl[j] = f2b(e[j] - b2f(h));
        }
        *(short4v*)(&sAh[row][kc]) = sh;
        *(short4v*)(&sAl[row][kc]) = sl;
      }
    } else {
      const bf16* Ah = (const bf16*)A0;
      const bf16* Al = (const bf16*)A1;
#pragma unroll
      for (int i = 0; i < 2; ++i) {
        const int li = i*256 + tid;
        const int row = li >> 2;
        const int kc  = (li & 3) << 3;
        int ga = m0 + row; if (ga >= M) ga = M - 1;
        const size_t goff = (size_t)ga*lda + k0 + kc;
        *(short8*)(&sAh[row][kc]) = *(const short8*)(Ah + goff);
        *(short8*)(&sAl[row][kc]) = *(const short8*)(Al + goff);
      }
    }
    // ---- stage B: linear loads from WT[N][K] (the ONLY change vs round 9) ----
#pragma unroll
    for (int i = 0; i < 2; ++i) {
      const int li = i*256 + tid;
      const int row = li >> 2;              // n offset 0..127
      const int kc  = (li & 3) << 3;        // k offset 0,8,16,24
      const size_t goff = (size_t)(n0 + row)*K + k0 + kc;
      *(short8*)(&sBh[row][kc]) = *(const short8*)(WTh + goff);
      *(short8*)(&sBl[row][kc]) = *(const short8*)(WTl + goff);
    }
    __syncthreads();

    short8 avh[4], avl[4], bvh[4], bvl[4];
#pragma unroll
    for (int i=0;i<4;i++) {
      avh[i] = *(const short8*)(&sAh[wr + i*16 + fr][fgk]);
      avl[i] = *(const short8*)(&sAl[wr + i*16 + fr][fgk]);
    }
#pragma unroll
    for (int j=0;j<4;j++) {
      bvh[j] = *(const short8*)(&sBh[wc + j*16 + fr][fgk]);
      bvl[j] = *(const short8*)(&sBl[wc + j*16 + fr][fgk]);
    }
#pragma unroll
    for (int i=0;i<4;i++)
#pragma unroll
      for (int j=0;j<4;j++) {
        acc[i][j] = __builtin_amdgcn_mfma_f32_16x16x32_bf16(avh[i], bvh[j], acc[i][j], 0,0,0);
        acc[i][j] = __builtin_amdgcn_mfma_f32_16x16x32_bf16(avl[i], bvh[j], acc[i][j], 0,0,0);
        acc[i][j] = __builtin_amdgcn_mfma_f32_16x16x32_bf16(avh[i], bvl[j], acc[i][j], 0,0,0);
      }
  }

  const int cr0 = (lane >> 4) << 2, cc = lane & 15;
#pragma unroll
  for (int i=0;i<4;i++) {
#pragma unroll
    for (int r=0;r<4;r++) {
      const int grow = m0 + wr + i*16 + cr0 + r;
      if (grow >= M) continue;
#pragma unroll
      for (int j=0;j<4;j++) {
        const int gcol = n0 + wc + j*16 + cc;
        float v = acc[i][j][r];
        if (BIAS) v += bias[gcol];
        if (RES)  v += res[(size_t)grow*ldres + gcol];
        if (OUTF) Cf[(size_t)grow*ldc + gcol] = v;
        if (OUTP) {
          short h = f2b(v);
          const size_t pidx = (size_t)grow*ldcp + gcol;
          Ch[pidx] = __builtin_bit_cast(bf16, h);
          Cl[pidx] = __float2bfloat16(v - b2f(h));
        }
      }
    }
  }
}

// ============ MFMA flash attention (round-9 identical) ============
template<bool MASK>
__global__ __launch_bounds__(256) void tb_fa(
    const bf16* __restrict__ Qh, const bf16* __restrict__ Ql, int ldq,
    const bf16* __restrict__ Kh, const bf16* __restrict__ Kl, int ldk,
    const bf16* __restrict__ Vh, const bf16* __restrict__ Vl, int ldv,
    float* __restrict__ O, int ldo,
    int Lq, int Lk, float scale)
{
  __shared__ bf16 sKh[32][72];
  __shared__ bf16 sKl[32][72];
  __shared__ bf16 sVTh[64][40];
  __shared__ bf16 sVTl[64][40];
  __shared__ bf16 sPh[4][16][48];
  __shared__ bf16 sPl[4][16][48];
  const int tid = threadIdx.x, lane = tid & 63, wid = tid >> 6;
  const int nq = Lq >> 6;
  int bid = blockIdx.x;
  const int qt = bid % nq; bid /= nq;
  const int hh = bid & 7; const int bb = bid >> 3;

  const bf16* Qbh = Qh + (size_t)bb*Lq*ldq + hh*64;
  const bf16* Qbl = Ql + (size_t)bb*Lq*ldq + hh*64;
  const bf16* Kbh = Kh + (size_t)bb*Lk*ldk + hh*64;
  const bf16* Kbl = Kl + (size_t)bb*Lk*ldk + hh*64;
  const bf16* Vbh = Vh + (size_t)bb*Lk*ldv + hh*64;
  const bf16* Vbl = Vl + (size_t)bb*Lk*ldv + hh*64;

  const int qrow = qt*64 + wid*16;
  const int fr = lane & 15, fg = lane >> 4;

  short8 aqh[2], aql[2];
#pragma unroll
  for (int c=0;c<2;c++){
    aqh[c] = *(const short8*)(Qbh + (size_t)(qrow + fr)*ldq + c*32 + fg*8);
    aql[c] = *(const short8*)(Qbl + (size_t)(qrow + fr)*ldq + c*32 + fg*8);
  }

  f32x4 oacc[4];
#pragma unroll
  for (int j=0;j<4;j++) oacc[j] = (f32x4)0.f;
  float mrun[4] = {-1e30f,-1e30f,-1e30f,-1e30f};
  float lrun[4] = {0.f,0.f,0.f,0.f};
  const float LOG2E = 1.44269504089f;

  const int nkc = (Lk + 31) >> 5;
  for (int kc = 0; kc < nkc; ++kc) {
    const int k0 = kc << 5;
    __syncthreads();
    {
      const int krow = tid >> 3;
      const int dh0  = (tid & 7) << 3;
      int gk = k0 + krow; if (gk > Lk-1) gk = Lk-1;
      short8 kh = *(const short8*)(Kbh + (size_t)gk*ldk + dh0);
      short8 kl = *(const short8*)(Kbl + (size_t)gk*ldk + dh0);
      short8 vh = *(const short8*)(Vbh + (size_t)gk*ldv + dh0);
      short8 vl = *(const short8*)(Vbl + (size_t)gk*ldv + dh0);
      *(short8*)(&sKh[krow][dh0]) = kh;
      *(short8*)(&sKl[krow][dh0]) = kl;
#pragma unroll
      for (int j=0;j<8;j++){
        sVTh[dh0+j][krow] = __builtin_bit_cast(bf16, (short)vh[j]);
        sVTl[dh0+j][krow] = __builtin_bit_cast(bf16, (short)vl[j]);
      }
    }
    __syncthreads();

    f32x4 sfr[2];
#pragma unroll
    for (int nt=0; nt<2; ++nt) {
      f32x4 sacc = (f32x4)0.f;
#pragma unroll
      for (int c=0;c<2;c++) {
        short8 bkh = *(const short8*)(&sKh[nt*16 + fr][c*32 + fg*8]);
        short8 bkl = *(const short8*)(&sKl[nt*16 + fr][c*32 + fg*8]);
        sacc = __builtin_amdgcn_mfma_f32_16x16x32_bf16(aqh[c], bkh, sacc, 0,0,0);
        sacc = __builtin_amdgcn_mfma_f32_16x16x32_bf16(aql[c], bkh, sacc, 0,0,0);
        sacc = __builtin_amdgcn_mfma_f32_16x16x32_bf16(aqh[c], bkl, sacc, 0,0,0);
      }
      sfr[nt] = sacc;
    }

    float pv0[4], pv1[4], mnew[4];
#pragma unroll
    for (int r=0;r<4;r++){
      float s0 = sfr[0][r]*scale, s1 = sfr[1][r]*scale;
      if (MASK) {
        if (k0 + fr      >= Lk) s0 = -1e30f;
        if (k0 + 16 + fr >= Lk) s1 = -1e30f;
      }
      pv0[r] = s0; pv1[r] = s1;
      float mx = fmaxf(s0, s1);
#pragma unroll
      for (int m=1;m<16;m<<=1) mx = fmaxf(mx, __shfl_xor(mx,m,64));
      mnew[r] = fmaxf(mrun[r], mx);
    }
#pragma unroll
    for (int r=0;r<4;r++){
      float sc = exp2f((mrun[r]-mnew[r])*LOG2E);
      mrun[r] = mnew[r];
      float p0 = exp2f((pv0[r]-mnew[r])*LOG2E);
      float p1 = exp2f((pv1[r]-mnew[r])*LOG2E);
      float ladd = p0 + p1;
#pragma unroll
      for (int m=1;m<16;m<<=1) ladd += __shfl_xor(ladd,m,64);
      lrun[r] = lrun[r]*sc + ladd;
#pragma unroll
      for (int j=0;j<4;j++) oacc[j][r] *= sc;
      short h0 = f2b(p0), h1 = f2b(p1);
      sPh[wid][fg*4+r][fr]       = __builtin_bit_cast(bf16, h0);
      sPh[wid][fg*4+r][16 + fr]  = __builtin_bit_cast(bf16, h1);
      sPl[wid][fg*4+r][fr]       = __float2bfloat16(p0 - b2f(h0));
      sPl[wid][fg*4+r][16 + fr]  = __float2bfloat16(p1 - b2f(h1));
    }

    asm volatile("s_waitcnt lgkmcnt(0)" ::: "memory");
    short8 pah = *(const short8*)(&sPh[wid][fr][fg*8]);
    short8 pal = *(const short8*)(&sPl[wid][fr][fg*8]);
#pragma unroll
    for (int ni=0; ni<4; ++ni) {
      short8 bvh = *(const short8*)(&sVTh[ni*16 + fr][fg*8]);
      short8 bvl = *(const short8*)(&sVTl[ni*16 + fr][fg*8]);
      oacc[ni] = __builtin_amdgcn_mfma_f32_16x16x32_bf16(pah, bvh, oacc[ni], 0,0,0);
      oacc[ni] = __builtin_amdgcn_mfma_f32_16x16x32_bf16(pal, bvh, oacc[ni], 0,0,0);
      oacc[ni] = __builtin_amdgcn_mfma_f32_16x16x32_bf16(pah, bvl, oacc[ni], 0,0,0);
    }
  }

  float inv[4];
#pragma unroll
  for (int r=0;r<4;r++) inv[r] = 1.f / lrun[r];
  const size_t orow0 = (size_t)bb*Lq + qt*64 + wid*16;
#pragma unroll
  for (int ni=0; ni<4; ++ni)
#pragma unroll
    for (int r=0;r<4;r++)
      O[(orow0 + fg*4 + r)*ldo + hh*64 + ni*16 + fr] = oacc[ni][r]*inv[r];
}

// ============ host (round-9 layout; weights now transposed content) ============
extern "C" void kernel_launch(void* const* d_in, const int* in_sizes, int n_in,
                              void* d_out, int out_size, void* d_ws, size_t ws_size,
                              hipStream_t stream)
{
  (void)in_sizes; (void)n_in; (void)out_size;
  printf("[tb11] build=r11-bisect-wtrans ws=%zu\n", ws_size);

  const float* x    = (const float*)d_in[0];
  const float* ctx  = (const float*)d_in[1];
  const float* ln1g = (const float*)d_in[2];
  const float* ln1b = (const float*)d_in[3];
  const float* ln2g = (const float*)d_in[4];
  const float* ln2b = (const float*)d_in[5];
  const float* ln3g = (const float*)d_in[6];
  const float* ln3b = (const float*)d_in[7];
  const float* wq1  = (const float*)d_in[8];
  const float* wk1  = (const float*)d_in[9];
  const float* wv1  = (const float*)d_in[10];
  const float* wo1  = (const float*)d_in[11];
  const float* bo1  = (const float*)d_in[12];
  const float* wq2  = (const float*)d_in[13];
  const float* wk2  = (const float*)d_in[14];
  const float* wv2  = (const float*)d_in[15];
  const float* wo2  = (const float*)d_in[16];
  const float* bo2  = (const float*)d_in[17];
  const float* w1   = (const float*)d_in[18];
  const float* b1   = (const float*)d_in[19];
  const float* w2   = (const float*)d_in[20];
  const float* b2   = (const float*)d_in[21];
  float* out = (float*)d_out;

  char* ws = (char*)d_ws;
  size_t off = 0;
  auto alloc = [&](size_t bytes)->void* {
    void* p = ws + off; off += (bytes + 255) & ~(size_t)255; return p;
  };
  auto wpair = [&](size_t elems, bf16*& h, bf16*& l){
    h = (bf16*)alloc(elems*2); l = (bf16*)alloc(elems*2);
  };
  // transposed [N][K] hi/lo weights (same byte sizes as round 9's flat pairs)
  bf16 *wq1h,*wq1l; wpair((size_t)512*512,  wq1h, wq1l);
  bf16 *wk1h,*wk1l; wpair((size_t)512*512,  wk1h, wk1l);
  bf16 *wv1h,*wv1l; wpair((size_t)512*512,  wv1h, wv1l);
  bf16 *wo1h,*wo1l; wpair((size_t)512*512,  wo1h, wo1l);
  bf16 *wq2h,*wq2l; wpair((size_t)512*512,  wq2h, wq2l);
  bf16 *wk2h,*wk2l; wpair((size_t)512*768,  wk2h, wk2l);
  bf16 *wv2h,*wv2l; wpair((size_t)512*768,  wv2h, wv2l);
  bf16 *wo2h,*wo2l; wpair((size_t)512*512,  wo2h, wo2l);
  bf16 *w1h, *w1l;  wpair((size_t)4096*512, w1h,  w1l);
  bf16 *w2h, *w2l;  wpair((size_t)512*2048, w2h,  w2l);

  float* h   = (float*)alloc((size_t)8192*512*4);
  float* x1  = (float*)alloc((size_t)8192*512*4);
  float* ob  = (float*)alloc((size_t)8192*512*4);

  char* U = (char*)alloc((size_t)134217728);
  const size_t SZ = (size_t)8192*512*2;
  bf16* qh = (bf16*)(U);        bf16* ql = (bf16*)(U + SZ);
  bf16* kh = (bf16*)(U + 2*SZ); bf16* kl = (bf16*)(U + 3*SZ);
  bf16* vh = (bf16*)(U + 4*SZ); bf16* vl = (bf16*)(U + 5*SZ);
  bf16* k2h = (bf16*)(U + 2*SZ);                 bf16* k2l = (bf16*)(U + 2*SZ + 1261568);
  bf16* v2h = (bf16*)(U + 2*SZ + 2*1261568);     bf16* v2l = (bf16*)(U + 2*SZ + 3*1261568);
  bf16* pbh = (bf16*)(U);       bf16* pbl = (bf16*)(U + (size_t)8192*4096*2);

  dim3 blk(256);

  // ---- weight transpose+split ([K][N] f32 -> [N][K] bf16 pair) ----
  wtrans<<<dim3(256),  blk, 0, stream>>>(wq1, wq1h, wq1l, 512, 512);
  wtrans<<<dim3(256),  blk, 0, stream>>>(wk1, wk1h, wk1l, 512, 512);
  wtrans<<<dim3(256),  blk, 0, stream>>>(wv1, wv1h, wv1l, 512, 512);
  wtrans<<<dim3(256),  blk, 0, stream>>>(wo1, wo1h, wo1l, 512, 512);
  wtrans<<<dim3(256),  blk, 0, stream>>>(wq2, wq2h, wq2l, 512, 512);
  wtrans<<<dim3(384),  blk, 0, stream>>>(wk2, wk2h, wk2l, 768, 512);
  wtrans<<<dim3(384),  blk, 0, stream>>>(wv2, wv2h, wv2l, 768, 512);
  wtrans<<<dim3(256),  blk, 0, stream>>>(wo2, wo2h, wo2l, 512, 512);
  wtrans<<<dim3(2048), blk, 0, stream>>>(w1,  w1h,  w1l,  512, 4096);
  wtrans<<<dim3(1024), blk, 0, stream>>>(w2,  w2h,  w2l,  2048, 512);

  // ---- self attention (separate Q/K/V GEMMs, round-9 structure) ----
  p5_ln<<<dim3(2048), blk, 0, stream>>>(x, ln1g, ln1b, h);
  mm11<0,false,false,false,true><<<dim3(64*4), blk, 0, stream>>>(
      h, nullptr, 512, wq1h, wq1l, nullptr, nullptr, 0,
      nullptr, 0, qh, ql, 512, 8192, 512, 512);
  mm11<0,false,false,false,true><<<dim3(64*4), blk, 0, stream>>>(
      h, nullptr, 512, wk1h, wk1l, nullptr, nullptr, 0,
      nullptr, 0, kh, kl, 512, 8192, 512, 512);
  mm11<0,false,false,false,true><<<dim3(64*4), blk, 0, stream>>>(
      h, nullptr, 512, wv1h, wv1l, nullptr, nullptr, 0,
      nullptr, 0, vh, vl, 512, 8192, 512, 512);
  tb_fa<false><<<dim3(1024), blk, 0, stream>>>(qh, ql, 512, kh, kl, 512, vh, vl, 512,
                                               ob, 512, 1024, 1024, 0.125f);
  mm11<0,true,true,true,false><<<dim3(64*4), blk, 0, stream>>>(
      ob, nullptr, 512, wo1h, wo1l, bo1, x, 512,
      x1, 512, nullptr, nullptr, 0, 8192, 512, 512);

  // ---- cross attention (separate K2/V2 GEMMs, round-9 structure) ----
  p5_ln<<<dim3(2048), blk, 0, stream>>>(x1, ln2g, ln2b, h);
  mm11<0,false,false,false,true><<<dim3(64*4), blk, 0, stream>>>(
      h, nullptr, 512, wq2h, wq2l, nullptr, nullptr, 0,
      nullptr, 0, qh, ql, 512, 8192, 512, 512);
  mm11<0,false,false,false,true><<<dim3(5*4), blk, 0, stream>>>(
      ctx, nullptr, 768, wk2h, wk2l, nullptr, nullptr, 0,
      nullptr, 0, k2h, k2l, 512, 616, 512, 768);
  mm11<0,false,false,false,true><<<dim3(5*4), blk, 0, stream>>>(
      ctx, nullptr, 768, wv2h, wv2l, nullptr, nullptr, 0,
      nullptr, 0, v2h, v2l, 512, 616, 512, 768);
  tb_fa<true><<<dim3(1024), blk, 0, stream>>>(qh, ql, 512, k2h, k2l, 512, v2h, v2l, 512,
                                              ob, 512, 1024, 77, 0.125f);
  mm11<0,true,true,true,false><<<dim3(64*4), blk, 0, stream>>>(
      ob, nullptr, 512, wo2h, wo2l, bo2, x1, 512,
      out, 512, nullptr, nullptr, 0, 8192, 512, 512);

  // ---- feed-forward (GEGLU), full width ----
  p5_ln<<<dim3(2048), blk, 0, stream>>>(out, ln3g, ln3b, h);
  mm11<0,true,false,false,true><<<dim3(64*32), blk, 0, stream>>>(
      h, nullptr, 512, w1h, w1l, b1, nullptr, 0,
      nullptr, 0, pbh, pbl, 4096, 8192, 4096, 512);
  tb_gg<<<dim3(8192), blk, 0, stream>>>(pbh, pbl);
  mm11<1,true,true,true,false><<<dim3(64*4), blk, 0, stream>>>(
      pbh, pbl, 4096, w2h, w2l, b2, out, 512,
      out, 512, nullptr, nullptr, 0, 8192, 512, 2048);
}